// Round 2
// baseline (1107.451 us; speedup 1.0000x reference)
//
#include <hip/hip_runtime.h>
#include <math.h>

#define NN 100000
#define EE 1600000

__device__ __forceinline__ float frelu(float v){ return v > 0.f ? v : 0.f; }

// ---------------------------------------------------------------------------
// CSR build: degree histogram -> exclusive scan -> bucket fill
// ---------------------------------------------------------------------------
__global__ __launch_bounds__(256) void count_deg(const int* __restrict__ dst,
                                                 int* __restrict__ counts)
{
    int e = blockIdx.x * 256 + threadIdx.x;   // grid is exact: EE/256
    atomicAdd(&counts[dst[e]], 1);
}

__global__ __launch_bounds__(256) void scan_blocks(const int* __restrict__ counts,
                                                   int* __restrict__ offsets,
                                                   int* __restrict__ bsums)
{
    __shared__ int lds[256];
    const int t = threadIdx.x, b = blockIdx.x;
    const int base = b * 1024 + t * 4;
    int v[4];
    #pragma unroll
    for (int i = 0; i < 4; i++) { int idx = base + i; v[i] = (idx < NN) ? counts[idx] : 0; }
    int s = v[0] + v[1] + v[2] + v[3];
    lds[t] = s;
    __syncthreads();
    for (int off = 1; off < 256; off <<= 1) {
        int y = (t >= off) ? lds[t - off] : 0;
        __syncthreads();
        lds[t] += y;
        __syncthreads();
    }
    int run = (t > 0) ? lds[t - 1] : 0;
    if (t == 255) bsums[b] = lds[255];
    #pragma unroll
    for (int i = 0; i < 4; i++) { int idx = base + i; if (idx < NN) offsets[idx] = run; run += v[i]; }
}

__global__ __launch_bounds__(128) void scan_sums(int* __restrict__ bsums)
{
    __shared__ int lds[128];
    const int t = threadIdx.x;
    lds[t] = (t < 98) ? bsums[t] : 0;
    __syncthreads();
    for (int off = 1; off < 128; off <<= 1) {
        int y = (t >= off) ? lds[t - off] : 0;
        __syncthreads();
        lds[t] += y;
        __syncthreads();
    }
    if (t < 98) bsums[t] = (t > 0) ? lds[t - 1] : 0;
}

__global__ __launch_bounds__(256) void scan_add(int* __restrict__ offsets,
                                                const int* __restrict__ bsums)
{
    const int b = blockIdx.x;
    const int add = bsums[b];
    const int base = b * 1024 + threadIdx.x * 4;
    #pragma unroll
    for (int i = 0; i < 4; i++) { int idx = base + i; if (idx < NN) offsets[idx] += add; }
}

// After this kernel, offsets[n] == END of node n's bucket (start = end - counts[n]).
__global__ __launch_bounds__(256) void fill_csr(const int* __restrict__ src,
                                                const int* __restrict__ dst,
                                                const float* __restrict__ ea,
                                                int* __restrict__ offsets,
                                                int* __restrict__ srcs,
                                                float* __restrict__ wq)
{
    int e = blockIdx.x * 256 + threadIdx.x;   // grid exact
    int p = atomicAdd(&offsets[dst[e]], 1);
    srcs[p] = src[e];
    wq[p]   = ea[e];
}

// ---------------------------------------------------------------------------
// Aggregation: one wave per node. 128 ch -> float2 per lane. No atomics.
// ---------------------------------------------------------------------------
__global__ __launch_bounds__(256) void agg_kernel(const float* __restrict__ h,
                                                  const int* __restrict__ srcs,
                                                  const float* __restrict__ wq,
                                                  const int* __restrict__ offsets,
                                                  const int* __restrict__ counts,
                                                  float* __restrict__ out)
{
    const int wid  = (blockIdx.x * 256 + threadIdx.x) >> 6;   // node id (grid exact: 25000*4)
    const int lane = threadIdx.x & 63;
    const int end = offsets[wid];
    const int cnt = counts[wid];
    float2 acc = make_float2(0.f, 0.f);
    const float2* __restrict__ h2 = (const float2*)h;
    for (int i = end - cnt; i < end; ++i) {
        const int   s = srcs[i];
        const float w = wq[i];
        float2 v = h2[(size_t)s * 64 + lane];
        acc.x = fmaf(w, v.x, acc.x);
        acc.y = fmaf(w, v.y, acc.y);
    }
    ((float2*)out)[(size_t)wid * 64 + lane] = acc;
}

// ---------------------------------------------------------------------------
// Dense tile helper: 32 nodes/block, thread computes 4 nodes x 4 channels.
// Per 4-k step: 4 broadcast ds_read_b128 + 4 coalesced global float4 W loads
// per 64 FMAs -> VALU-bound.
// ---------------------------------------------------------------------------
template<int K, int LDW, int LDSROW>
__device__ __forceinline__ void gemm_tile(const float* __restrict__ Wg,
                                          const float* lds,
                                          int n0, int c0, float acc[4][4])
{
    for (int k = 0; k < K; k += 4) {
        float4 w0 = *(const float4*)(Wg + (size_t)(k + 0) * LDW + c0);
        float4 w1 = *(const float4*)(Wg + (size_t)(k + 1) * LDW + c0);
        float4 w2 = *(const float4*)(Wg + (size_t)(k + 2) * LDW + c0);
        float4 w3 = *(const float4*)(Wg + (size_t)(k + 3) * LDW + c0);
        #pragma unroll
        for (int n = 0; n < 4; n++) {
            float4 xv = *(const float4*)(lds + (n0 + n) * LDSROW + k);
            acc[n][0] += xv.x * w0.x + xv.y * w1.x + xv.z * w2.x + xv.w * w3.x;
            acc[n][1] += xv.x * w0.y + xv.y * w1.y + xv.z * w2.y + xv.w * w3.y;
            acc[n][2] += xv.x * w0.z + xv.y * w1.z + xv.z * w2.z + xv.w * w3.z;
            acc[n][3] += xv.x * w0.w + xv.y * w1.w + xv.z * w2.w + xv.w * w3.w;
        }
    }
}

__device__ __forceinline__ void zero_acc(float acc[4][4])
{
    #pragma unroll
    for (int n = 0; n < 4; n++)
        #pragma unroll
        for (int j = 0; j < 4; j++) acc[n][j] = 0.f;
}

// ---------------------------------------------------------------------------
// Encoder: h = relu(relu(x@W1+b1)@W2+b2), fused two layers per block.
// ---------------------------------------------------------------------------
__global__ __launch_bounds__(256) void enc_kernel(const float* __restrict__ x,
                                                  const float* __restrict__ W1, const float* __restrict__ b1,
                                                  const float* __restrict__ W2, const float* __restrict__ b2,
                                                  float* __restrict__ out)
{
    __shared__ __align__(16) float xs[32 * 256];
    __shared__ __align__(16) float h1[32 * 128];
    const int t = threadIdx.x;
    const int nbase = blockIdx.x * 32;
    {
        const float4* s = (const float4*)(x + (size_t)nbase * 256);
        float4* d = (float4*)xs;
        #pragma unroll
        for (int i = 0; i < 8; i++) d[t + i * 256] = s[t + i * 256];
    }
    __syncthreads();
    const int c0 = (t & 31) * 4;
    const int n0 = (t >> 5) * 4;
    float acc[4][4];
    zero_acc(acc);
    gemm_tile<256, 128, 256>(W1, xs, n0, c0, acc);
    {
        float4 bv = *(const float4*)(b1 + c0);
        #pragma unroll
        for (int n = 0; n < 4; n++) {
            float4 r;
            r.x = frelu(acc[n][0] + bv.x);
            r.y = frelu(acc[n][1] + bv.y);
            r.z = frelu(acc[n][2] + bv.z);
            r.w = frelu(acc[n][3] + bv.w);
            *(float4*)&h1[(n0 + n) * 128 + c0] = r;
        }
    }
    __syncthreads();
    zero_acc(acc);
    gemm_tile<128, 128, 128>(W2, h1, n0, c0, acc);
    {
        float4 bv = *(const float4*)(b2 + c0);
        #pragma unroll
        for (int n = 0; n < 4; n++) {
            float4 r;
            r.x = frelu(acc[n][0] + bv.x);
            r.y = frelu(acc[n][1] + bv.y);
            r.z = frelu(acc[n][2] + bv.z);
            r.w = frelu(acc[n][3] + bv.w);
            *(float4*)(out + (size_t)(nbase + n0 + n) * 128 + c0) = r;
        }
    }
}

// ---------------------------------------------------------------------------
// GraphConv combine: out = relu(agg@Wrel + brel + h@Wroot). In-place over agg.
// ---------------------------------------------------------------------------
__global__ __launch_bounds__(256) void conv_kernel(const float* __restrict__ agg,
                                                   const float* __restrict__ h,
                                                   const float* __restrict__ Wrel, const float* __restrict__ brel,
                                                   const float* __restrict__ Wroot,
                                                   float* __restrict__ out)
{
    __shared__ __align__(16) float as_[32 * 128];
    __shared__ __align__(16) float hs[32 * 128];
    const int t = threadIdx.x;
    const int nbase = blockIdx.x * 32;
    {
        const float4* sa = (const float4*)(agg + (size_t)nbase * 128);
        const float4* sh = (const float4*)(h + (size_t)nbase * 128);
        float4* da = (float4*)as_;
        float4* dh = (float4*)hs;
        #pragma unroll
        for (int i = 0; i < 4; i++) { da[t + i * 256] = sa[t + i * 256]; dh[t + i * 256] = sh[t + i * 256]; }
    }
    __syncthreads();
    const int c0 = (t & 31) * 4;
    const int n0 = (t >> 5) * 4;
    float acc[4][4];
    zero_acc(acc);
    gemm_tile<128, 128, 128>(Wrel, as_, n0, c0, acc);
    gemm_tile<128, 128, 128>(Wroot, hs, n0, c0, acc);
    {
        float4 bv = *(const float4*)(brel + c0);
        #pragma unroll
        for (int n = 0; n < 4; n++) {
            float4 r;
            r.x = frelu(acc[n][0] + bv.x);
            r.y = frelu(acc[n][1] + bv.y);
            r.z = frelu(acc[n][2] + bv.z);
            r.w = frelu(acc[n][3] + bv.w);
            *(float4*)(out + (size_t)(nbase + n0 + n) * 128 + c0) = r;
        }
    }
}

// ---------------------------------------------------------------------------
// Heads: mu = h@Wmu+bmu, logvar = h@Wlv+blv (no activation).
// 128 threads: 8 node-tiles x 16 ch-tiles over 64 output channels (mu|lv).
// ---------------------------------------------------------------------------
__global__ __launch_bounds__(128) void heads_kernel(const float* __restrict__ h,
                                                    const float* __restrict__ Wmu, const float* __restrict__ bmu,
                                                    const float* __restrict__ Wlv, const float* __restrict__ blv,
                                                    float* __restrict__ out)
{
    __shared__ __align__(16) float hs[32 * 128];
    const int t = threadIdx.x;
    const int nbase = blockIdx.x * 32;
    {
        const float4* s = (const float4*)(h + (size_t)nbase * 128);
        float4* d = (float4*)hs;
        #pragma unroll
        for (int i = 0; i < 8; i++) d[t + i * 128] = s[t + i * 128];
    }
    __syncthreads();
    const int c0 = (t & 15) * 4;    // 0..60 over [mu(32) | lv(32)]
    const int n0 = (t >> 4) * 4;
    const bool is_mu = (c0 < 32);
    const float* W = is_mu ? Wmu : Wlv;
    const float* b = is_mu ? bmu : blv;
    const int cc = c0 & 31;
    float acc[4][4];
    zero_acc(acc);
    for (int k = 0; k < 128; k += 4) {
        float4 w0 = *(const float4*)(W + (size_t)(k + 0) * 32 + cc);
        float4 w1 = *(const float4*)(W + (size_t)(k + 1) * 32 + cc);
        float4 w2 = *(const float4*)(W + (size_t)(k + 2) * 32 + cc);
        float4 w3 = *(const float4*)(W + (size_t)(k + 3) * 32 + cc);
        #pragma unroll
        for (int n = 0; n < 4; n++) {
            float4 xv = *(const float4*)(&hs[(n0 + n) * 128 + k]);
            acc[n][0] += xv.x * w0.x + xv.y * w1.x + xv.z * w2.x + xv.w * w3.x;
            acc[n][1] += xv.x * w0.y + xv.y * w1.y + xv.z * w2.y + xv.w * w3.y;
            acc[n][2] += xv.x * w0.z + xv.y * w1.z + xv.z * w2.z + xv.w * w3.z;
            acc[n][3] += xv.x * w0.w + xv.y * w1.w + xv.z * w2.w + xv.w * w3.w;
        }
    }
    float4 bv = *(const float4*)(b + cc);
    float* base = out + (is_mu ? (size_t)25600000 : (size_t)28800000);
    #pragma unroll
    for (int n = 0; n < 4; n++) {
        float4 r;
        r.x = acc[n][0] + bv.x;
        r.y = acc[n][1] + bv.y;
        r.z = acc[n][2] + bv.z;
        r.w = acc[n][3] + bv.w;
        *(float4*)(base + (size_t)(nbase + n0 + n) * 32 + cc) = r;
    }
}

// z = mu + eps * exp(0.5*logvar)
__global__ __launch_bounds__(256) void reparam_kernel(const float* __restrict__ eps,
                                                      float* __restrict__ out)
{
    int i = blockIdx.x * 256 + threadIdx.x;   // grid exact: 12500*256 = 3.2M
    float mu = out[25600000 + i];
    float lv = out[28800000 + i];
    out[32000000 + i] = fmaf(eps[i], expf(0.5f * lv), mu);
}

// ---------------------------------------------------------------------------
// Decoder: x_recon = relu(z@Wd1+bd1)@Wd2 + bd2, fused.
// ---------------------------------------------------------------------------
__global__ __launch_bounds__(256) void dec_kernel(const float* __restrict__ z,
                                                  const float* __restrict__ Wd1, const float* __restrict__ bd1,
                                                  const float* __restrict__ Wd2, const float* __restrict__ bd2,
                                                  float* __restrict__ out)
{
    __shared__ __align__(16) float zs[32 * 32];
    __shared__ __align__(16) float hd[32 * 128];
    const int t = threadIdx.x;
    const int nbase = blockIdx.x * 32;
    {
        const float4* s = (const float4*)(z + (size_t)nbase * 32);
        float4* d = (float4*)zs;
        d[t] = s[t];   // 256 float4 == 32*32 floats
    }
    __syncthreads();
    const int c0 = (t & 31) * 4;
    const int n0 = (t >> 5) * 4;
    float acc[4][4];
    zero_acc(acc);
    gemm_tile<32, 128, 32>(Wd1, zs, n0, c0, acc);
    {
        float4 bv = *(const float4*)(bd1 + c0);
        #pragma unroll
        for (int n = 0; n < 4; n++) {
            float4 r;
            r.x = frelu(acc[n][0] + bv.x);
            r.y = frelu(acc[n][1] + bv.y);
            r.z = frelu(acc[n][2] + bv.z);
            r.w = frelu(acc[n][3] + bv.w);
            *(float4*)&hd[(n0 + n) * 128 + c0] = r;
        }
    }
    __syncthreads();
    #pragma unroll
    for (int rep = 0; rep < 2; rep++) {
        const int c0r = c0 + rep * 128;
        zero_acc(acc);
        for (int k = 0; k < 128; k += 4) {
            float4 w0 = *(const float4*)(Wd2 + (size_t)(k + 0) * 256 + c0r);
            float4 w1 = *(const float4*)(Wd2 + (size_t)(k + 1) * 256 + c0r);
            float4 w2 = *(const float4*)(Wd2 + (size_t)(k + 2) * 256 + c0r);
            float4 w3 = *(const float4*)(Wd2 + (size_t)(k + 3) * 256 + c0r);
            #pragma unroll
            for (int n = 0; n < 4; n++) {
                float4 xv = *(const float4*)(&hd[(n0 + n) * 128 + k]);
                acc[n][0] += xv.x * w0.x + xv.y * w1.x + xv.z * w2.x + xv.w * w3.x;
                acc[n][1] += xv.x * w0.y + xv.y * w1.y + xv.z * w2.y + xv.w * w3.y;
                acc[n][2] += xv.x * w0.z + xv.y * w1.z + xv.z * w2.z + xv.w * w3.z;
                acc[n][3] += xv.x * w0.w + xv.y * w1.w + xv.z * w2.w + xv.w * w3.w;
            }
        }
        float4 bv = *(const float4*)(bd2 + c0r);
        #pragma unroll
        for (int n = 0; n < 4; n++) {
            float4 r;
            r.x = acc[n][0] + bv.x;
            r.y = acc[n][1] + bv.y;
            r.z = acc[n][2] + bv.z;
            r.w = acc[n][3] + bv.w;
            *(float4*)(out + (size_t)(nbase + n0 + n) * 256 + c0r) = r;
        }
    }
}

// ---------------------------------------------------------------------------
extern "C" void kernel_launch(void* const* d_in, const int* in_sizes, int n_in,
                              void* d_out, int out_size, void* d_ws, size_t ws_size,
                              hipStream_t stream)
{
    const float* x     = (const float*)d_in[0];
    const int*   ei    = (const int*)d_in[1];
    const float* ea    = (const float*)d_in[2];
    const float* W1    = (const float*)d_in[3];
    const float* b1    = (const float*)d_in[4];
    const float* W2    = (const float*)d_in[5];
    const float* b2    = (const float*)d_in[6];
    const float* Wrel1 = (const float*)d_in[7];
    const float* brel1 = (const float*)d_in[8];
    const float* Wroot1= (const float*)d_in[9];
    const float* Wrel2 = (const float*)d_in[10];
    const float* brel2 = (const float*)d_in[11];
    const float* Wroot2= (const float*)d_in[12];
    const float* Wmu   = (const float*)d_in[13];
    const float* bmu   = (const float*)d_in[14];
    const float* Wlv   = (const float*)d_in[15];
    const float* blv   = (const float*)d_in[16];
    const float* Wd1   = (const float*)d_in[17];
    const float* bd1   = (const float*)d_in[18];
    const float* Wd2   = (const float*)d_in[19];
    const float* bd2   = (const float*)d_in[20];
    const float* eps   = (const float*)d_in[21];
    float* out = (float*)d_out;

    // h ping-pong buffers live in d_out's x_recon region ([0, 25.6M) floats),
    // which is dead until dec_kernel runs last. Keeps d_ws usage to ~13.6 MB.
    float* B0 = out;                    // [N,128] = 12.8M floats
    float* B1 = out + 12800000;         // [N,128] = 12.8M floats

    char* ws = (char*)d_ws;
    int*   counts  = (int*)  (ws);                 // [N]      400 KB
    int*   offsets = (int*)  (ws + 400000);        // [N]      400 KB
    int*   bsums   = (int*)  (ws + 800000);        // [98]
    int*   srcs    = (int*)  (ws + 801024);        // [E]      6.4 MB
    float* wq      = (float*)(ws + 7201024);       // [E]      6.4 MB (end ~13.6 MB)

    const int* src = ei;          // edge_index row 0
    const int* dst = ei + EE;     // edge_index row 1

    // --- CSR build (reused by both conv layers) ---
    hipMemsetAsync(counts, 0, NN * sizeof(int), stream);
    count_deg<<<EE / 256, 256, 0, stream>>>(dst, counts);
    scan_blocks<<<98, 256, 0, stream>>>(counts, offsets, bsums);
    scan_sums<<<1, 128, 0, stream>>>(bsums);
    scan_add<<<98, 256, 0, stream>>>(offsets, bsums);
    fill_csr<<<EE / 256, 256, 0, stream>>>(src, dst, ea, offsets, srcs, wq);

    // --- forward pass ---
    enc_kernel<<<3125, 256, 0, stream>>>(x, W1, b1, W2, b2, B0);
    agg_kernel<<<25000, 256, 0, stream>>>(B0, srcs, wq, offsets, counts, B1);
    conv_kernel<<<3125, 256, 0, stream>>>(B1, B0, Wrel1, brel1, Wroot1, B1);
    agg_kernel<<<25000, 256, 0, stream>>>(B1, srcs, wq, offsets, counts, B0);
    conv_kernel<<<3125, 256, 0, stream>>>(B0, B1, Wrel2, brel2, Wroot2, B0);
    heads_kernel<<<3125, 128, 0, stream>>>(B0, Wmu, bmu, Wlv, blv, out);
    reparam_kernel<<<12500, 256, 0, stream>>>(eps, out);
    dec_kernel<<<3125, 256, 0, stream>>>(out + 32000000, Wd1, bd1, Wd2, bd2, out);
}

// Round 3
// 756.872 us; speedup vs baseline: 1.4632x; 1.4632x over previous
//
#include <hip/hip_runtime.h>
#include <math.h>

#define NN 100000
#define EE 1600000

typedef _Float16 f16;
typedef __attribute__((ext_vector_type(8))) _Float16 f16x8;
typedef __attribute__((ext_vector_type(4))) float f32x4;

__device__ __forceinline__ float frelu(float v){ return v > 0.f ? v : 0.f; }

__device__ __forceinline__ f32x4 mfma16(f16x8 a, f16x8 b, f32x4 c){
    return __builtin_amdgcn_mfma_f32_16x16x32_f16(a, b, c, 0, 0, 0);
}

// ---------------------------------------------------------------------------
// CSR build: degree histogram -> exclusive scan -> bucket fill (unchanged)
// ---------------------------------------------------------------------------
__global__ __launch_bounds__(256) void count_deg(const int* __restrict__ dst,
                                                 int* __restrict__ counts)
{
    int e = blockIdx.x * 256 + threadIdx.x;
    atomicAdd(&counts[dst[e]], 1);
}

__global__ __launch_bounds__(256) void scan_blocks(const int* __restrict__ counts,
                                                   int* __restrict__ offsets,
                                                   int* __restrict__ bsums)
{
    __shared__ int lds[256];
    const int t = threadIdx.x, b = blockIdx.x;
    const int base = b * 1024 + t * 4;
    int v[4];
    #pragma unroll
    for (int i = 0; i < 4; i++) { int idx = base + i; v[i] = (idx < NN) ? counts[idx] : 0; }
    int s = v[0] + v[1] + v[2] + v[3];
    lds[t] = s;
    __syncthreads();
    for (int off = 1; off < 256; off <<= 1) {
        int y = (t >= off) ? lds[t - off] : 0;
        __syncthreads();
        lds[t] += y;
        __syncthreads();
    }
    int run = (t > 0) ? lds[t - 1] : 0;
    if (t == 255) bsums[b] = lds[255];
    #pragma unroll
    for (int i = 0; i < 4; i++) { int idx = base + i; if (idx < NN) offsets[idx] = run; run += v[i]; }
}

__global__ __launch_bounds__(128) void scan_sums(int* __restrict__ bsums)
{
    __shared__ int lds[128];
    const int t = threadIdx.x;
    lds[t] = (t < 98) ? bsums[t] : 0;
    __syncthreads();
    for (int off = 1; off < 128; off <<= 1) {
        int y = (t >= off) ? lds[t - off] : 0;
        __syncthreads();
        lds[t] += y;
        __syncthreads();
    }
    if (t < 98) bsums[t] = (t > 0) ? lds[t - 1] : 0;
}

__global__ __launch_bounds__(256) void scan_add(int* __restrict__ offsets,
                                                const int* __restrict__ bsums)
{
    const int b = blockIdx.x;
    const int add = bsums[b];
    const int base = b * 1024 + threadIdx.x * 4;
    #pragma unroll
    for (int i = 0; i < 4; i++) { int idx = base + i; if (idx < NN) offsets[idx] += add; }
}

__global__ __launch_bounds__(256) void fill_csr(const int* __restrict__ src,
                                                const int* __restrict__ dst,
                                                const float* __restrict__ ea,
                                                int* __restrict__ offsets,
                                                int* __restrict__ srcs,
                                                float* __restrict__ wq)
{
    int e = blockIdx.x * 256 + threadIdx.x;
    int p = atomicAdd(&offsets[dst[e]], 1);
    srcs[p] = src[e];
    wq[p]   = ea[e];
}

// ---------------------------------------------------------------------------
// Aggregation: one wave per node, f32, no atomics (unchanged)
// ---------------------------------------------------------------------------
__global__ __launch_bounds__(256) void agg_kernel(const float* __restrict__ h,
                                                  const int* __restrict__ srcs,
                                                  const float* __restrict__ wq,
                                                  const int* __restrict__ offsets,
                                                  const int* __restrict__ counts,
                                                  float* __restrict__ out)
{
    const int wid  = (blockIdx.x * 256 + threadIdx.x) >> 6;
    const int lane = threadIdx.x & 63;
    const int end = offsets[wid];
    const int cnt = counts[wid];
    float2 acc = make_float2(0.f, 0.f);
    const float2* __restrict__ h2 = (const float2*)h;
    for (int i = end - cnt; i < end; ++i) {
        const int   s = srcs[i];
        const float w = wq[i];
        float2 v = h2[(size_t)s * 64 + lane];
        acc.x = fmaf(w, v.x, acc.x);
        acc.y = fmaf(w, v.y, acc.y);
    }
    ((float2*)out)[(size_t)wid * 64 + lane] = acc;
}

// ---------------------------------------------------------------------------
// Weight packing into MFMA fragment order (fp16).
// pack[(kk*CT+ct)*64 + lane][j]  =  W[kk*32 + (lane>>4)*8 + j][ct*16 + (lane&15)]
// Segments (fp16 elems): enc1 @0 (32768), enc2 @32768 (16384), conv1 @49152
// (32768), conv2 @81920 (32768), dec1 @114688 (4096), dec2 @118784 (32768).
// ---------------------------------------------------------------------------
__global__ __launch_bounds__(256) void prep_pack(const float* __restrict__ W1,
                                                 const float* __restrict__ W2,
                                                 const float* __restrict__ Wrel1,
                                                 const float* __restrict__ Wroot1,
                                                 const float* __restrict__ Wrel2,
                                                 const float* __restrict__ Wroot2,
                                                 const float* __restrict__ Wd1,
                                                 const float* __restrict__ Wd2,
                                                 f16* __restrict__ pack)
{
    int t = blockIdx.x * 256 + threadIdx.x;   // grid exact: 151552/256 = 592
    float v;
    if (t < 32768) {                          // enc1: W1 [256,128], CT=8
        int l = t;
        int j = l & 7, lane = (l >> 3) & 63, ct = (l >> 9) & 7, kk = l >> 12;
        int k = kk * 32 + ((lane >> 4) << 3) + j, c = (ct << 4) + (lane & 15);
        v = W1[k * 128 + c];
    } else if (t < 49152) {                   // enc2: W2 [128,128], CT=8
        int l = t - 32768;
        int j = l & 7, lane = (l >> 3) & 63, ct = (l >> 9) & 7, kk = l >> 12;
        int k = kk * 32 + ((lane >> 4) << 3) + j, c = (ct << 4) + (lane & 15);
        v = W2[k * 128 + c];
    } else if (t < 81920) {                   // conv1: [Wrel1;Wroot1] K=256, CT=8
        int l = t - 49152;
        int j = l & 7, lane = (l >> 3) & 63, ct = (l >> 9) & 7, kk = l >> 12;
        int k = kk * 32 + ((lane >> 4) << 3) + j, c = (ct << 4) + (lane & 15);
        v = (k < 128) ? Wrel1[k * 128 + c] : Wroot1[(k - 128) * 128 + c];
    } else if (t < 114688) {                  // conv2
        int l = t - 81920;
        int j = l & 7, lane = (l >> 3) & 63, ct = (l >> 9) & 7, kk = l >> 12;
        int k = kk * 32 + ((lane >> 4) << 3) + j, c = (ct << 4) + (lane & 15);
        v = (k < 128) ? Wrel2[k * 128 + c] : Wroot2[(k - 128) * 128 + c];
    } else if (t < 118784) {                  // dec1: Wd1 [32,128], CT=8, kk=0
        int l = t - 114688;
        int j = l & 7, lane = (l >> 3) & 63, ct = (l >> 9) & 7;
        int k = ((lane >> 4) << 3) + j, c = (ct << 4) + (lane & 15);
        v = Wd1[k * 128 + c];
    } else {                                  // dec2: Wd2 [128,256], CT=16
        int l = t - 118784;
        int j = l & 7, lane = (l >> 3) & 63, ct = (l >> 9) & 15, kk = l >> 13;
        int k = kk * 32 + ((lane >> 4) << 3) + j, c = (ct << 4) + (lane & 15);
        v = Wd2[k * 256 + c];
    }
    pack[t] = (f16)v;
}

// ---------------------------------------------------------------------------
// MFMA GEMM building blocks. 64 nodes/block, 4 waves, wave = 16 nodes.
// LDS A tiles: fp16 row-major, row stride = C + 8 halves (pad => bank-free).
// ---------------------------------------------------------------------------
template<int C>
__device__ __forceinline__ void stage_tile(const float* __restrict__ src, int nbase,
                                           f16* lds, int ldr, int colofs)
{
    const int t = threadIdx.x;
    #pragma unroll
    for (int i = 0; i < (64 * C / 4) / 256; i++) {
        int elem = t + i * 256;
        int row = elem / (C / 4);
        int c4  = elem % (C / 4);
        int srow = nbase + row; if (srow >= NN) srow = NN - 1;
        float4 v = *(const float4*)(src + (size_t)srow * C + c4 * 4);
        union { f16 h[4]; uint2 u; } cv;
        cv.h[0] = (f16)v.x; cv.h[1] = (f16)v.y; cv.h[2] = (f16)v.z; cv.h[3] = (f16)v.w;
        *(uint2*)&lds[row * ldr + colofs + c4 * 4] = cv.u;
    }
}

template<int K, int CT>
__device__ __forceinline__ void wave_gemm(const f16* lds, int ldr,
                                          const f16x8* __restrict__ wp, f32x4 acc[CT])
{
    const int lane = threadIdx.x & 63;
    const int wrow = (threadIdx.x >> 6) * 16;
    const int arow = wrow + (lane & 15);
    const int kofs = (lane >> 4) << 3;
    #pragma unroll
    for (int kk = 0; kk < K / 32; kk++) {
        f16x8 a = *(const f16x8*)&lds[arow * ldr + kk * 32 + kofs];
        #pragma unroll
        for (int ct = 0; ct < CT; ct++) {
            f16x8 b = wp[(kk * CT + ct) * 64 + lane];
            acc[ct] = mfma16(a, b, acc[ct]);
        }
    }
}

template<int CT>
__device__ __forceinline__ void zacc(f32x4 acc[CT])
{
    #pragma unroll
    for (int ct = 0; ct < CT; ct++) acc[ct] = f32x4{0.f, 0.f, 0.f, 0.f};
}

// C/D layout (m89): col = lane&15, row = (lane>>4)*4 + reg
template<int CT, bool RELU>
__device__ __forceinline__ void store_f32(float* __restrict__ dst, int OUTC, int nbase,
                                          const float* __restrict__ bias, f32x4 acc[CT])
{
    const int lane = threadIdx.x & 63;
    const int wrow = (threadIdx.x >> 6) * 16;
    #pragma unroll
    for (int ct = 0; ct < CT; ct++) {
        int c = ct * 16 + (lane & 15);
        float bv = bias[c];
        #pragma unroll
        for (int r = 0; r < 4; r++) {
            int node = nbase + wrow + ((lane >> 4) << 2) + r;
            if (node < NN) {
                float v = acc[ct][r] + bv;
                if (RELU) v = frelu(v);
                dst[(size_t)node * OUTC + c] = v;
            }
        }
    }
}

template<int CT>
__device__ __forceinline__ void store_lds_f16(f16* lds, int ldr,
                                              const float* __restrict__ bias, f32x4 acc[CT])
{
    const int lane = threadIdx.x & 63;
    const int wrow = (threadIdx.x >> 6) * 16;
    #pragma unroll
    for (int ct = 0; ct < CT; ct++) {
        int c = ct * 16 + (lane & 15);
        float bv = bias[c];
        #pragma unroll
        for (int r = 0; r < 4; r++) {
            int row = wrow + ((lane >> 4) << 2) + r;
            lds[row * ldr + c] = (f16)frelu(acc[ct][r] + bv);
        }
    }
}

// ---------------------------------------------------------------------------
// Encoder: h = relu(relu(x@W1+b1)@W2+b2), two fused MFMA layers.
// ---------------------------------------------------------------------------
__global__ __launch_bounds__(256) void enc_mfma(const float* __restrict__ x,
                                                const f16x8* __restrict__ wp1,
                                                const f16x8* __restrict__ wp2,
                                                const float* __restrict__ b1,
                                                const float* __restrict__ b2,
                                                float* __restrict__ out)
{
    __shared__ __align__(16) f16 xs[64 * 264];
    __shared__ __align__(16) f16 h1[64 * 136];
    const int nbase = blockIdx.x * 64;
    stage_tile<256>(x, nbase, xs, 264, 0);
    __syncthreads();
    f32x4 acc[8];
    zacc<8>(acc);
    wave_gemm<256, 8>(xs, 264, wp1, acc);
    store_lds_f16<8>(h1, 136, b1, acc);
    __syncthreads();
    zacc<8>(acc);
    wave_gemm<128, 8>(h1, 136, wp2, acc);
    store_f32<8, true>(out, 128, nbase, b2, acc);
}

// ---------------------------------------------------------------------------
// GraphConv combine: out = relu([agg|h] @ [Wrel;Wroot] + brel), K=256 MFMA.
// ---------------------------------------------------------------------------
__global__ __launch_bounds__(256) void conv_mfma(const float* __restrict__ agg,
                                                 const float* __restrict__ h,
                                                 const f16x8* __restrict__ wp,
                                                 const float* __restrict__ brel,
                                                 float* __restrict__ out)
{
    __shared__ __align__(16) f16 as_[64 * 264];
    const int nbase = blockIdx.x * 64;
    stage_tile<128>(agg, nbase, as_, 264, 0);
    stage_tile<128>(h,   nbase, as_, 264, 128);
    __syncthreads();
    f32x4 acc[8];
    zacc<8>(acc);
    wave_gemm<256, 8>(as_, 264, wp, acc);
    store_f32<8, true>(out, 128, nbase, brel, acc);
}

// ---------------------------------------------------------------------------
// Heads (kept f32 for accuracy): mu/logvar from h. 32 nodes/block.
// ---------------------------------------------------------------------------
__global__ __launch_bounds__(128) void heads_kernel(const float* __restrict__ h,
                                                    const float* __restrict__ Wmu, const float* __restrict__ bmu,
                                                    const float* __restrict__ Wlv, const float* __restrict__ blv,
                                                    float* __restrict__ out)
{
    __shared__ __align__(16) float hs[32 * 128];
    const int t = threadIdx.x;
    const int nbase = blockIdx.x * 32;
    {
        const float4* s = (const float4*)(h + (size_t)nbase * 128);
        float4* d = (float4*)hs;
        #pragma unroll
        for (int i = 0; i < 8; i++) d[t + i * 128] = s[t + i * 128];
    }
    __syncthreads();
    const int c0 = (t & 15) * 4;
    const int n0 = (t >> 4) * 4;
    const bool is_mu = (c0 < 32);
    const float* W = is_mu ? Wmu : Wlv;
    const float* b = is_mu ? bmu : blv;
    const int cc = c0 & 31;
    float acc[4][4];
    #pragma unroll
    for (int n = 0; n < 4; n++)
        #pragma unroll
        for (int j = 0; j < 4; j++) acc[n][j] = 0.f;
    for (int k = 0; k < 128; k += 4) {
        float4 w0 = *(const float4*)(W + (size_t)(k + 0) * 32 + cc);
        float4 w1 = *(const float4*)(W + (size_t)(k + 1) * 32 + cc);
        float4 w2 = *(const float4*)(W + (size_t)(k + 2) * 32 + cc);
        float4 w3 = *(const float4*)(W + (size_t)(k + 3) * 32 + cc);
        #pragma unroll
        for (int n = 0; n < 4; n++) {
            float4 xv = *(const float4*)(&hs[(n0 + n) * 128 + k]);
            acc[n][0] += xv.x * w0.x + xv.y * w1.x + xv.z * w2.x + xv.w * w3.x;
            acc[n][1] += xv.x * w0.y + xv.y * w1.y + xv.z * w2.y + xv.w * w3.y;
            acc[n][2] += xv.x * w0.z + xv.y * w1.z + xv.z * w2.z + xv.w * w3.z;
            acc[n][3] += xv.x * w0.w + xv.y * w1.w + xv.z * w2.w + xv.w * w3.w;
        }
    }
    float4 bv = *(const float4*)(b + cc);
    float* base = out + (is_mu ? (size_t)25600000 : (size_t)28800000);
    #pragma unroll
    for (int n = 0; n < 4; n++) {
        float4 r;
        r.x = acc[n][0] + bv.x;
        r.y = acc[n][1] + bv.y;
        r.z = acc[n][2] + bv.z;
        r.w = acc[n][3] + bv.w;
        *(float4*)(base + (size_t)(nbase + n0 + n) * 32 + cc) = r;
    }
}

// z = mu + eps * exp(0.5*logvar)
__global__ __launch_bounds__(256) void reparam_kernel(const float* __restrict__ eps,
                                                      float* __restrict__ out)
{
    int i = blockIdx.x * 256 + threadIdx.x;
    float mu = out[25600000 + i];
    float lv = out[28800000 + i];
    out[32000000 + i] = fmaf(eps[i], expf(0.5f * lv), mu);
}

// ---------------------------------------------------------------------------
// Decoder: x_recon = relu(z@Wd1+bd1)@Wd2 + bd2, two fused MFMA layers.
// ---------------------------------------------------------------------------
__global__ __launch_bounds__(256) void dec_mfma(const float* __restrict__ z,
                                                const f16x8* __restrict__ wp1,
                                                const float* __restrict__ bd1,
                                                const f16x8* __restrict__ wp2,
                                                const float* __restrict__ bd2,
                                                float* __restrict__ out)
{
    __shared__ __align__(16) f16 zs[64 * 40];
    __shared__ __align__(16) f16 hd[64 * 136];
    const int nbase = blockIdx.x * 64;
    stage_tile<32>(z, nbase, zs, 40, 0);
    __syncthreads();
    f32x4 acc[8];
    zacc<8>(acc);
    wave_gemm<32, 8>(zs, 40, wp1, acc);
    store_lds_f16<8>(hd, 136, bd1, acc);
    __syncthreads();
    f32x4 acc2[16];
    zacc<16>(acc2);
    wave_gemm<128, 16>(hd, 136, wp2, acc2);
    store_f32<16, false>(out, 256, nbase, bd2, acc2);
}

// ---------------------------------------------------------------------------
extern "C" void kernel_launch(void* const* d_in, const int* in_sizes, int n_in,
                              void* d_out, int out_size, void* d_ws, size_t ws_size,
                              hipStream_t stream)
{
    const float* x     = (const float*)d_in[0];
    const int*   ei    = (const int*)d_in[1];
    const float* ea    = (const float*)d_in[2];
    const float* W1    = (const float*)d_in[3];
    const float* b1    = (const float*)d_in[4];
    const float* W2    = (const float*)d_in[5];
    const float* b2    = (const float*)d_in[6];
    const float* Wrel1 = (const float*)d_in[7];
    const float* brel1 = (const float*)d_in[8];
    const float* Wroot1= (const float*)d_in[9];
    const float* Wrel2 = (const float*)d_in[10];
    const float* brel2 = (const float*)d_in[11];
    const float* Wroot2= (const float*)d_in[12];
    const float* Wmu   = (const float*)d_in[13];
    const float* bmu   = (const float*)d_in[14];
    const float* Wlv   = (const float*)d_in[15];
    const float* blv   = (const float*)d_in[16];
    const float* Wd1   = (const float*)d_in[17];
    const float* bd1   = (const float*)d_in[18];
    const float* Wd2   = (const float*)d_in[19];
    const float* bd2   = (const float*)d_in[20];
    const float* eps   = (const float*)d_in[21];
    float* out = (float*)d_out;

    // h ping-pong buffers live in d_out's x_recon region (dead until dec_mfma).
    float* B0 = out;                    // [N,128]
    float* B1 = out + 12800000;         // [N,128]

    char* ws = (char*)d_ws;
    int*   counts  = (int*)  (ws);                 // [N]
    int*   offsets = (int*)  (ws + 400000);        // [N]
    int*   bsums   = (int*)  (ws + 800000);        // [98]
    int*   srcs    = (int*)  (ws + 801024);        // [E]
    float* wq      = (float*)(ws + 7201024);       // [E]
    f16*   pack    = (f16*)  (ws + 13601024);      // 151552 halves = 303 KB

    const f16x8* wp_enc1  = (const f16x8*)(pack);
    const f16x8* wp_enc2  = (const f16x8*)(pack + 32768);
    const f16x8* wp_conv1 = (const f16x8*)(pack + 49152);
    const f16x8* wp_conv2 = (const f16x8*)(pack + 81920);
    const f16x8* wp_dec1  = (const f16x8*)(pack + 114688);
    const f16x8* wp_dec2  = (const f16x8*)(pack + 118784);

    const int* src = ei;          // edge_index row 0
    const int* dst = ei + EE;     // edge_index row 1

    // --- weight packing + CSR build ---
    prep_pack<<<592, 256, 0, stream>>>(W1, W2, Wrel1, Wroot1, Wrel2, Wroot2, Wd1, Wd2, pack);
    hipMemsetAsync(counts, 0, NN * sizeof(int), stream);
    count_deg<<<EE / 256, 256, 0, stream>>>(dst, counts);
    scan_blocks<<<98, 256, 0, stream>>>(counts, offsets, bsums);
    scan_sums<<<1, 128, 0, stream>>>(bsums);
    scan_add<<<98, 256, 0, stream>>>(offsets, bsums);
    fill_csr<<<EE / 256, 256, 0, stream>>>(src, dst, ea, offsets, srcs, wq);

    // --- forward pass ---
    enc_mfma<<<1563, 256, 0, stream>>>(x, wp_enc1, wp_enc2, b1, b2, B0);
    agg_kernel<<<25000, 256, 0, stream>>>(B0, srcs, wq, offsets, counts, B1);
    conv_mfma<<<1563, 256, 0, stream>>>(B1, B0, wp_conv1, brel1, B1);
    agg_kernel<<<25000, 256, 0, stream>>>(B1, srcs, wq, offsets, counts, B0);
    conv_mfma<<<1563, 256, 0, stream>>>(B0, B1, wp_conv2, brel2, B0);
    heads_kernel<<<3125, 128, 0, stream>>>(B0, Wmu, bmu, Wlv, blv, out);
    reparam_kernel<<<12500, 256, 0, stream>>>(eps, out);
    dec_mfma<<<1563, 256, 0, stream>>>(out + 32000000, wp_dec1, bd1, wp_dec2, bd2, out);
}

// Round 4
// 642.360 us; speedup vs baseline: 1.7240x; 1.1783x over previous
//
#include <hip/hip_runtime.h>
#include <math.h>

#define NN 100000
#define EE 1600000

typedef _Float16 f16;
typedef __attribute__((ext_vector_type(2))) _Float16 f16x2;
typedef __attribute__((ext_vector_type(8))) _Float16 f16x8;
typedef __attribute__((ext_vector_type(4))) float f32x4;
typedef unsigned int u32;

union H2 { u32 u; f16x2 h; };

__device__ __forceinline__ float frelu(float v){ return v > 0.f ? v : 0.f; }

__device__ __forceinline__ f32x4 mfma16(f16x8 a, f16x8 b, f32x4 c){
    return __builtin_amdgcn_mfma_f32_16x16x32_f16(a, b, c, 0, 0, 0);
}

// ---------------------------------------------------------------------------
// CSR build: degree histogram -> exclusive scan -> bucket fill
// ---------------------------------------------------------------------------
__global__ __launch_bounds__(256) void count_deg(const int* __restrict__ dst,
                                                 int* __restrict__ counts)
{
    int e = blockIdx.x * 256 + threadIdx.x;
    atomicAdd(&counts[dst[e]], 1);
}

__global__ __launch_bounds__(256) void scan_blocks(const int* __restrict__ counts,
                                                   int* __restrict__ offsets,
                                                   int* __restrict__ bsums)
{
    __shared__ int lds[256];
    const int t = threadIdx.x, b = blockIdx.x;
    const int base = b * 1024 + t * 4;
    int v[4];
    #pragma unroll
    for (int i = 0; i < 4; i++) { int idx = base + i; v[i] = (idx < NN) ? counts[idx] : 0; }
    int s = v[0] + v[1] + v[2] + v[3];
    lds[t] = s;
    __syncthreads();
    for (int off = 1; off < 256; off <<= 1) {
        int y = (t >= off) ? lds[t - off] : 0;
        __syncthreads();
        lds[t] += y;
        __syncthreads();
    }
    int run = (t > 0) ? lds[t - 1] : 0;
    if (t == 255) bsums[b] = lds[255];
    #pragma unroll
    for (int i = 0; i < 4; i++) { int idx = base + i; if (idx < NN) offsets[idx] = run; run += v[i]; }
}

__global__ __launch_bounds__(128) void scan_sums(int* __restrict__ bsums)
{
    __shared__ int lds[128];
    const int t = threadIdx.x;
    lds[t] = (t < 98) ? bsums[t] : 0;
    __syncthreads();
    for (int off = 1; off < 128; off <<= 1) {
        int y = (t >= off) ? lds[t - off] : 0;
        __syncthreads();
        lds[t] += y;
        __syncthreads();
    }
    if (t < 98) bsums[t] = (t > 0) ? lds[t - 1] : 0;
}

__global__ __launch_bounds__(256) void scan_add(int* __restrict__ offsets,
                                                const int* __restrict__ bsums)
{
    const int b = blockIdx.x;
    const int add = bsums[b];
    const int base = b * 1024 + threadIdx.x * 4;
    #pragma unroll
    for (int i = 0; i < 4; i++) { int idx = base + i; if (idx < NN) offsets[idx] += add; }
}

__global__ __launch_bounds__(256) void fill_csr(const int* __restrict__ src,
                                                const int* __restrict__ dst,
                                                const float* __restrict__ ea,
                                                int* __restrict__ offsets,
                                                int* __restrict__ srcs,
                                                float* __restrict__ wq)
{
    int e = blockIdx.x * 256 + threadIdx.x;
    int p = atomicAdd(&offsets[dst[e]], 1);
    srcs[p] = src[e];
    wq[p]   = ea[e];
}

// ---------------------------------------------------------------------------
// Aggregation over fp16 h: one wave per node, lane = 2 channels (4B), f32 acc.
// ---------------------------------------------------------------------------
__global__ __launch_bounds__(256) void agg_f16(const f16* __restrict__ h,
                                               const int* __restrict__ srcs,
                                               const float* __restrict__ wq,
                                               const int* __restrict__ offsets,
                                               const int* __restrict__ counts,
                                               f16* __restrict__ out)
{
    const int wid  = (blockIdx.x * 256 + threadIdx.x) >> 6;
    const int lane = threadIdx.x & 63;
    const int end = offsets[wid];
    const int cnt = counts[wid];
    float2 acc = make_float2(0.f, 0.f);
    const u32* __restrict__ h4 = (const u32*)h;   // f16x2 chunks, 64 per row
    int i = end - cnt;
    for (; i + 2 <= end; i += 2) {
        const int s0 = srcs[i],   s1 = srcs[i + 1];
        const float w0 = wq[i],   w1 = wq[i + 1];
        H2 p0, p1;
        p0.u = h4[(size_t)s0 * 64 + lane];
        p1.u = h4[(size_t)s1 * 64 + lane];
        acc.x = fmaf(w0, (float)p0.h.x, acc.x);
        acc.y = fmaf(w0, (float)p0.h.y, acc.y);
        acc.x = fmaf(w1, (float)p1.h.x, acc.x);
        acc.y = fmaf(w1, (float)p1.h.y, acc.y);
    }
    if (i < end) {
        const int s0 = srcs[i];
        const float w0 = wq[i];
        H2 p0; p0.u = h4[(size_t)s0 * 64 + lane];
        acc.x = fmaf(w0, (float)p0.h.x, acc.x);
        acc.y = fmaf(w0, (float)p0.h.y, acc.y);
    }
    H2 r; r.h.x = (f16)acc.x; r.h.y = (f16)acc.y;
    ((u32*)out)[(size_t)wid * 64 + lane] = r.u;
}

// ---------------------------------------------------------------------------
// Weight packing into MFMA fragment order (fp16).
// pack[(kk*CT+ct)*64 + lane][j] = W[kk*32 + (lane>>4)*8 + j][ct*16 + (lane&15)]
// ---------------------------------------------------------------------------
__global__ __launch_bounds__(256) void prep_pack(const float* __restrict__ W1,
                                                 const float* __restrict__ W2,
                                                 const float* __restrict__ Wrel1,
                                                 const float* __restrict__ Wroot1,
                                                 const float* __restrict__ Wrel2,
                                                 const float* __restrict__ Wroot2,
                                                 const float* __restrict__ Wd1,
                                                 const float* __restrict__ Wd2,
                                                 f16* __restrict__ pack)
{
    int t = blockIdx.x * 256 + threadIdx.x;   // grid exact: 151552/256 = 592
    float v;
    if (t < 32768) {                          // enc1: W1 [256,128], CT=8
        int l = t;
        int j = l & 7, lane = (l >> 3) & 63, ct = (l >> 9) & 7, kk = l >> 12;
        int k = kk * 32 + ((lane >> 4) << 3) + j, c = (ct << 4) + (lane & 15);
        v = W1[k * 128 + c];
    } else if (t < 49152) {                   // enc2: W2 [128,128], CT=8
        int l = t - 32768;
        int j = l & 7, lane = (l >> 3) & 63, ct = (l >> 9) & 7, kk = l >> 12;
        int k = kk * 32 + ((lane >> 4) << 3) + j, c = (ct << 4) + (lane & 15);
        v = W2[k * 128 + c];
    } else if (t < 81920) {                   // conv1: [Wrel1;Wroot1] K=256, CT=8
        int l = t - 49152;
        int j = l & 7, lane = (l >> 3) & 63, ct = (l >> 9) & 7, kk = l >> 12;
        int k = kk * 32 + ((lane >> 4) << 3) + j, c = (ct << 4) + (lane & 15);
        v = (k < 128) ? Wrel1[k * 128 + c] : Wroot1[(k - 128) * 128 + c];
    } else if (t < 114688) {                  // conv2
        int l = t - 81920;
        int j = l & 7, lane = (l >> 3) & 63, ct = (l >> 9) & 7, kk = l >> 12;
        int k = kk * 32 + ((lane >> 4) << 3) + j, c = (ct << 4) + (lane & 15);
        v = (k < 128) ? Wrel2[k * 128 + c] : Wroot2[(k - 128) * 128 + c];
    } else if (t < 118784) {                  // dec1: Wd1 [32,128], CT=8, kk=0
        int l = t - 114688;
        int j = l & 7, lane = (l >> 3) & 63, ct = (l >> 9) & 7;
        int k = ((lane >> 4) << 3) + j, c = (ct << 4) + (lane & 15);
        v = Wd1[k * 128 + c];
    } else {                                  // dec2: Wd2 [128,256], CT=16
        int l = t - 118784;
        int j = l & 7, lane = (l >> 3) & 63, ct = (l >> 9) & 15, kk = l >> 13;
        int k = kk * 32 + ((lane >> 4) << 3) + j, c = (ct << 4) + (lane & 15);
        v = Wd2[k * 256 + c];
    }
    pack[t] = (f16)v;
}

// ---------------------------------------------------------------------------
// MFMA GEMM building blocks. 64 nodes/block, 4 waves, wave = 16 nodes.
// LDS A tiles: fp16 row-major, padded row stride (bank-conflict-free).
// ---------------------------------------------------------------------------
template<int C>
__device__ __forceinline__ void stage_tile(const float* __restrict__ src, int nbase,
                                           f16* lds, int ldr, int colofs)
{
    const int t = threadIdx.x;
    #pragma unroll
    for (int i = 0; i < (64 * C / 4) / 256; i++) {
        int elem = t + i * 256;
        int row = elem / (C / 4);
        int c4  = elem % (C / 4);
        int srow = nbase + row; if (srow >= NN) srow = NN - 1;
        float4 v = *(const float4*)(src + (size_t)srow * C + c4 * 4);
        union { f16 h[4]; uint2 u; } cv;
        cv.h[0] = (f16)v.x; cv.h[1] = (f16)v.y; cv.h[2] = (f16)v.z; cv.h[3] = (f16)v.w;
        *(uint2*)&lds[row * ldr + colofs + c4 * 4] = cv.u;
    }
}

template<int C>
__device__ __forceinline__ void stage_tile_f16(const f16* __restrict__ src, int nbase,
                                               f16* lds, int ldr, int colofs)
{
    const int t = threadIdx.x;
    #pragma unroll
    for (int i = 0; i < (64 * C / 4) / 256; i++) {
        int elem = t + i * 256;
        int row = elem / (C / 4);
        int c4  = elem % (C / 4);
        int srow = nbase + row; if (srow >= NN) srow = NN - 1;
        uint2 v = *(const uint2*)(src + (size_t)srow * C + c4 * 4);
        *(uint2*)&lds[row * ldr + colofs + c4 * 4] = v;
    }
}

template<int K, int CT>
__device__ __forceinline__ void wave_gemm(const f16* lds, int ldr,
                                          const f16x8* __restrict__ wp, f32x4 acc[CT])
{
    const int lane = threadIdx.x & 63;
    const int wrow = (threadIdx.x >> 6) * 16;
    const int arow = wrow + (lane & 15);
    const int kofs = (lane >> 4) << 3;
    #pragma unroll
    for (int kk = 0; kk < K / 32; kk++) {
        f16x8 a = *(const f16x8*)&lds[arow * ldr + kk * 32 + kofs];
        #pragma unroll
        for (int ct = 0; ct < CT; ct++) {
            f16x8 b = wp[(kk * CT + ct) * 64 + lane];
            acc[ct] = mfma16(a, b, acc[ct]);
        }
    }
}

template<int CT>
__device__ __forceinline__ void zacc(f32x4 acc[CT])
{
    #pragma unroll
    for (int ct = 0; ct < CT; ct++) acc[ct] = f32x4{0.f, 0.f, 0.f, 0.f};
}

// C/D layout (m89): col = lane&15, row = (lane>>4)*4 + reg
template<int CT, bool RELU>
__device__ __forceinline__ void store_f32(float* __restrict__ dst, int OUTC, int nbase,
                                          const float* __restrict__ bias, f32x4 acc[CT])
{
    const int lane = threadIdx.x & 63;
    const int wrow = (threadIdx.x >> 6) * 16;
    #pragma unroll
    for (int ct = 0; ct < CT; ct++) {
        int c = ct * 16 + (lane & 15);
        float bv = bias[c];
        #pragma unroll
        for (int r = 0; r < 4; r++) {
            int node = nbase + wrow + ((lane >> 4) << 2) + r;
            if (node < NN) {
                float v = acc[ct][r] + bv;
                if (RELU) v = frelu(v);
                dst[(size_t)node * OUTC + c] = v;
            }
        }
    }
}

template<int CT, bool RELU>
__device__ __forceinline__ void store_f16g(f16* __restrict__ dst, int OUTC, int nbase,
                                           const float* __restrict__ bias, f32x4 acc[CT])
{
    const int lane = threadIdx.x & 63;
    const int wrow = (threadIdx.x >> 6) * 16;
    #pragma unroll
    for (int ct = 0; ct < CT; ct++) {
        int c = ct * 16 + (lane & 15);
        float bv = bias[c];
        #pragma unroll
        for (int r = 0; r < 4; r++) {
            int node = nbase + wrow + ((lane >> 4) << 2) + r;
            if (node < NN) {
                float v = acc[ct][r] + bv;
                if (RELU) v = frelu(v);
                dst[(size_t)node * OUTC + c] = (f16)v;
            }
        }
    }
}

template<int CT>
__device__ __forceinline__ void store_lds_f16(f16* lds, int ldr,
                                              const float* __restrict__ bias, f32x4 acc[CT])
{
    const int lane = threadIdx.x & 63;
    const int wrow = (threadIdx.x >> 6) * 16;
    #pragma unroll
    for (int ct = 0; ct < CT; ct++) {
        int c = ct * 16 + (lane & 15);
        float bv = bias[c];
        #pragma unroll
        for (int r = 0; r < 4; r++) {
            int row = wrow + ((lane >> 4) << 2) + r;
            lds[row * ldr + c] = (f16)frelu(acc[ct][r] + bv);
        }
    }
}

// ---------------------------------------------------------------------------
// Encoder: h = relu(relu(x@W1+b1)@W2+b2) -> fp16 h.
// ---------------------------------------------------------------------------
__global__ __launch_bounds__(256) void enc_mfma(const float* __restrict__ x,
                                                const f16x8* __restrict__ wp1,
                                                const f16x8* __restrict__ wp2,
                                                const float* __restrict__ b1,
                                                const float* __restrict__ b2,
                                                f16* __restrict__ out)
{
    __shared__ __align__(16) f16 xs[64 * 264];
    __shared__ __align__(16) f16 h1[64 * 136];
    const int nbase = blockIdx.x * 64;
    stage_tile<256>(x, nbase, xs, 264, 0);
    __syncthreads();
    f32x4 acc[8];
    zacc<8>(acc);
    wave_gemm<256, 8>(xs, 264, wp1, acc);
    store_lds_f16<8>(h1, 136, b1, acc);
    __syncthreads();
    zacc<8>(acc);
    wave_gemm<128, 8>(h1, 136, wp2, acc);
    store_f16g<8, true>(out, 128, nbase, b2, acc);
}

// ---------------------------------------------------------------------------
// GraphConv combine: out = relu([agg|h] @ [Wrel;Wroot] + brel), fp16 in/out.
// ---------------------------------------------------------------------------
__global__ __launch_bounds__(256) void conv_mfma(const f16* __restrict__ agg,
                                                 const f16* __restrict__ h,
                                                 const f16x8* __restrict__ wp,
                                                 const float* __restrict__ brel,
                                                 f16* __restrict__ out)
{
    __shared__ __align__(16) f16 as_[64 * 264];
    const int nbase = blockIdx.x * 64;
    stage_tile_f16<128>(agg, nbase, as_, 264, 0);
    stage_tile_f16<128>(h,   nbase, as_, 264, 128);
    __syncthreads();
    f32x4 acc[8];
    zacc<8>(acc);
    wave_gemm<256, 8>(as_, 264, wp, acc);
    store_f16g<8, true>(out, 128, nbase, brel, acc);
}

// ---------------------------------------------------------------------------
// Heads (f32 math, f16 h input): mu/logvar. 32 nodes/block, 128 threads.
// ---------------------------------------------------------------------------
__global__ __launch_bounds__(128) void heads_kernel(const f16* __restrict__ h,
                                                    const float* __restrict__ Wmu, const float* __restrict__ bmu,
                                                    const float* __restrict__ Wlv, const float* __restrict__ blv,
                                                    float* __restrict__ out)
{
    __shared__ __align__(16) float hs[32 * 128];
    const int t = threadIdx.x;
    const int nbase = blockIdx.x * 32;
    #pragma unroll
    for (int i = 0; i < 8; i++) {
        int elem = t + i * 128;
        int row = elem >> 5;
        int c4  = elem & 31;
        union { f16 h[4]; uint2 u; } cv;
        cv.u = *(const uint2*)(h + (size_t)(nbase + row) * 128 + c4 * 4);
        float4 v = make_float4((float)cv.h[0], (float)cv.h[1], (float)cv.h[2], (float)cv.h[3]);
        *(float4*)&hs[row * 128 + c4 * 4] = v;
    }
    __syncthreads();
    const int c0 = (t & 15) * 4;
    const int n0 = (t >> 4) * 4;
    const bool is_mu = (c0 < 32);
    const float* W = is_mu ? Wmu : Wlv;
    const float* b = is_mu ? bmu : blv;
    const int cc = c0 & 31;
    float acc[4][4];
    #pragma unroll
    for (int n = 0; n < 4; n++)
        #pragma unroll
        for (int j = 0; j < 4; j++) acc[n][j] = 0.f;
    for (int k = 0; k < 128; k += 4) {
        float4 w0 = *(const float4*)(W + (size_t)(k + 0) * 32 + cc);
        float4 w1 = *(const float4*)(W + (size_t)(k + 1) * 32 + cc);
        float4 w2 = *(const float4*)(W + (size_t)(k + 2) * 32 + cc);
        float4 w3 = *(const float4*)(W + (size_t)(k + 3) * 32 + cc);
        #pragma unroll
        for (int n = 0; n < 4; n++) {
            float4 xv = *(const float4*)(&hs[(n0 + n) * 128 + k]);
            acc[n][0] += xv.x * w0.x + xv.y * w1.x + xv.z * w2.x + xv.w * w3.x;
            acc[n][1] += xv.x * w0.y + xv.y * w1.y + xv.z * w2.y + xv.w * w3.y;
            acc[n][2] += xv.x * w0.z + xv.y * w1.z + xv.z * w2.z + xv.w * w3.z;
            acc[n][3] += xv.x * w0.w + xv.y * w1.w + xv.z * w2.w + xv.w * w3.w;
        }
    }
    float4 bv = *(const float4*)(b + cc);
    float* base = out + (is_mu ? (size_t)25600000 : (size_t)28800000);
    #pragma unroll
    for (int n = 0; n < 4; n++) {
        float4 r;
        r.x = acc[n][0] + bv.x;
        r.y = acc[n][1] + bv.y;
        r.z = acc[n][2] + bv.z;
        r.w = acc[n][3] + bv.w;
        *(float4*)(base + (size_t)(nbase + n0 + n) * 32 + cc) = r;
    }
}

// z = mu + eps * exp(0.5*logvar)
__global__ __launch_bounds__(256) void reparam_kernel(const float* __restrict__ eps,
                                                      float* __restrict__ out)
{
    int i = blockIdx.x * 256 + threadIdx.x;
    float mu = out[25600000 + i];
    float lv = out[28800000 + i];
    out[32000000 + i] = fmaf(eps[i], expf(0.5f * lv), mu);
}

// ---------------------------------------------------------------------------
// Decoder: x_recon = relu(z@Wd1+bd1)@Wd2 + bd2, two fused MFMA layers, f32 out.
// ---------------------------------------------------------------------------
__global__ __launch_bounds__(256) void dec_mfma(const float* __restrict__ z,
                                                const f16x8* __restrict__ wp1,
                                                const float* __restrict__ bd1,
                                                const f16x8* __restrict__ wp2,
                                                const float* __restrict__ bd2,
                                                float* __restrict__ out)
{
    __shared__ __align__(16) f16 zs[64 * 40];
    __shared__ __align__(16) f16 hd[64 * 136];
    const int nbase = blockIdx.x * 64;
    stage_tile<32>(z, nbase, zs, 40, 0);
    __syncthreads();
    f32x4 acc[8];
    zacc<8>(acc);
    wave_gemm<32, 8>(zs, 40, wp1, acc);
    store_lds_f16<8>(hd, 136, bd1, acc);
    __syncthreads();
    f32x4 acc2[16];
    zacc<16>(acc2);
    wave_gemm<128, 16>(hd, 136, wp2, acc2);
    store_f32<16, false>(out, 256, nbase, bd2, acc2);
}

// ---------------------------------------------------------------------------
extern "C" void kernel_launch(void* const* d_in, const int* in_sizes, int n_in,
                              void* d_out, int out_size, void* d_ws, size_t ws_size,
                              hipStream_t stream)
{
    const float* x     = (const float*)d_in[0];
    const int*   ei    = (const int*)d_in[1];
    const float* ea    = (const float*)d_in[2];
    const float* W1    = (const float*)d_in[3];
    const float* b1    = (const float*)d_in[4];
    const float* W2    = (const float*)d_in[5];
    const float* b2    = (const float*)d_in[6];
    const float* Wrel1 = (const float*)d_in[7];
    const float* brel1 = (const float*)d_in[8];
    const float* Wroot1= (const float*)d_in[9];
    const float* Wrel2 = (const float*)d_in[10];
    const float* brel2 = (const float*)d_in[11];
    const float* Wroot2= (const float*)d_in[12];
    const float* Wmu   = (const float*)d_in[13];
    const float* bmu   = (const float*)d_in[14];
    const float* Wlv   = (const float*)d_in[15];
    const float* blv   = (const float*)d_in[16];
    const float* Wd1   = (const float*)d_in[17];
    const float* bd1   = (const float*)d_in[18];
    const float* Wd2   = (const float*)d_in[19];
    const float* bd2   = (const float*)d_in[20];
    const float* eps   = (const float*)d_in[21];
    float* out = (float*)d_out;

    // fp16 h ping-pong buffers live in d_out's x_recon region (dead until dec).
    f16* B0 = (f16*)out;                // [N,128] f16 = 25.6 MB
    f16* B1 = B0 + 12800000;            // [N,128] f16

    char* ws = (char*)d_ws;
    int*   counts  = (int*)  (ws);                 // [N]
    int*   offsets = (int*)  (ws + 400000);        // [N]
    int*   bsums   = (int*)  (ws + 800000);        // [98]
    int*   srcs    = (int*)  (ws + 801024);        // [E]
    float* wq      = (float*)(ws + 7201024);       // [E]
    f16*   pack    = (f16*)  (ws + 13601024);      // 151552 halves

    const f16x8* wp_enc1  = (const f16x8*)(pack);
    const f16x8* wp_enc2  = (const f16x8*)(pack + 32768);
    const f16x8* wp_conv1 = (const f16x8*)(pack + 49152);
    const f16x8* wp_conv2 = (const f16x8*)(pack + 81920);
    const f16x8* wp_dec1  = (const f16x8*)(pack + 114688);
    const f16x8* wp_dec2  = (const f16x8*)(pack + 118784);

    const int* src = ei;          // edge_index row 0
    const int* dst = ei + EE;     // edge_index row 1

    // --- weight packing + CSR build ---
    prep_pack<<<592, 256, 0, stream>>>(W1, W2, Wrel1, Wroot1, Wrel2, Wroot2, Wd1, Wd2, pack);
    hipMemsetAsync(counts, 0, NN * sizeof(int), stream);
    count_deg<<<EE / 256, 256, 0, stream>>>(dst, counts);
    scan_blocks<<<98, 256, 0, stream>>>(counts, offsets, bsums);
    scan_sums<<<1, 128, 0, stream>>>(bsums);
    scan_add<<<98, 256, 0, stream>>>(offsets, bsums);
    fill_csr<<<EE / 256, 256, 0, stream>>>(src, dst, ea, offsets, srcs, wq);

    // --- forward pass ---
    enc_mfma<<<1563, 256, 0, stream>>>(x, wp_enc1, wp_enc2, b1, b2, B0);
    agg_f16<<<25000, 256, 0, stream>>>(B0, srcs, wq, offsets, counts, B1);
    conv_mfma<<<1563, 256, 0, stream>>>(B1, B0, wp_conv1, brel1, B1);
    agg_f16<<<25000, 256, 0, stream>>>(B1, srcs, wq, offsets, counts, B0);
    conv_mfma<<<1563, 256, 0, stream>>>(B0, B1, wp_conv2, brel2, B0);
    heads_kernel<<<3125, 128, 0, stream>>>(B0, Wmu, bmu, Wlv, blv, out);
    reparam_kernel<<<12500, 256, 0, stream>>>(eps, out);
    dec_mfma<<<1563, 256, 0, stream>>>(out + 32000000, wp_dec1, bd1, wp_dec2, bd2, out);
}

// Round 5
// 527.235 us; speedup vs baseline: 2.1005x; 1.2184x over previous
//
#include <hip/hip_runtime.h>
#include <math.h>

#define NN 100000
#define EE 1600000

typedef _Float16 f16;
typedef __attribute__((ext_vector_type(2))) _Float16 f16x2;
typedef __attribute__((ext_vector_type(8))) _Float16 f16x8;
typedef __attribute__((ext_vector_type(4))) float f32x4;
typedef unsigned int u32;

__device__ __forceinline__ float frelu(float v){ return v > 0.f ? v : 0.f; }

__device__ __forceinline__ f32x4 mfma16(f16x8 a, f16x8 b, f32x4 c){
    return __builtin_amdgcn_mfma_f32_16x16x32_f16(a, b, c, 0, 0, 0);
}

// ---------------------------------------------------------------------------
// CSR build: degree histogram -> exclusive scan -> bucket fill
// ---------------------------------------------------------------------------
__global__ __launch_bounds__(256) void count_deg(const int* __restrict__ dst,
                                                 int* __restrict__ counts)
{
    int e = blockIdx.x * 256 + threadIdx.x;
    atomicAdd(&counts[dst[e]], 1);
}

__global__ __launch_bounds__(256) void scan_blocks(const int* __restrict__ counts,
                                                   int* __restrict__ offsets,
                                                   int* __restrict__ bsums)
{
    __shared__ int lds[256];
    const int t = threadIdx.x, b = blockIdx.x;
    const int base = b * 1024 + t * 4;
    int v[4];
    #pragma unroll
    for (int i = 0; i < 4; i++) { int idx = base + i; v[i] = (idx < NN) ? counts[idx] : 0; }
    int s = v[0] + v[1] + v[2] + v[3];
    lds[t] = s;
    __syncthreads();
    for (int off = 1; off < 256; off <<= 1) {
        int y = (t >= off) ? lds[t - off] : 0;
        __syncthreads();
        lds[t] += y;
        __syncthreads();
    }
    int run = (t > 0) ? lds[t - 1] : 0;
    if (t == 255) bsums[b] = lds[255];
    #pragma unroll
    for (int i = 0; i < 4; i++) { int idx = base + i; if (idx < NN) offsets[idx] = run; run += v[i]; }
}

__global__ __launch_bounds__(128) void scan_sums(int* __restrict__ bsums)
{
    __shared__ int lds[128];
    const int t = threadIdx.x;
    lds[t] = (t < 98) ? bsums[t] : 0;
    __syncthreads();
    for (int off = 1; off < 128; off <<= 1) {
        int y = (t >= off) ? lds[t - off] : 0;
        __syncthreads();
        lds[t] += y;
        __syncthreads();
    }
    if (t < 98) bsums[t] = (t > 0) ? lds[t - 1] : 0;
}

__global__ __launch_bounds__(256) void scan_add(int* __restrict__ offsets,
                                                const int* __restrict__ bsums)
{
    const int b = blockIdx.x;
    const int add = bsums[b];
    const int base = b * 1024 + threadIdx.x * 4;
    #pragma unroll
    for (int i = 0; i < 4; i++) { int idx = base + i; if (idx < NN) offsets[idx] += add; }
}

// Pairs: {src, weight-bits} per edge, bucketed by dst.
__global__ __launch_bounds__(256) void fill_csr(const int* __restrict__ src,
                                                const int* __restrict__ dst,
                                                const float* __restrict__ ea,
                                                int* __restrict__ offsets,
                                                int2* __restrict__ pairs)
{
    int e = blockIdx.x * 256 + threadIdx.x;
    int p = atomicAdd(&offsets[dst[e]], 1);
    pairs[p] = make_int2(src[e], __float_as_int(ea[e]));
}

// ---------------------------------------------------------------------------
// Aggregation: quarter-wave (16 lanes x 16B) per node. 4 nodes per wave,
// 1KB of gather data in flight per wave-instruction, v_fma_mix accumulate.
// ---------------------------------------------------------------------------
__global__ __launch_bounds__(256) void agg_q(const f16* __restrict__ h,
                                             const int2* __restrict__ pairs,
                                             const int* __restrict__ offsets,
                                             const int* __restrict__ counts,
                                             f16* __restrict__ out)
{
    const int gt   = blockIdx.x * 256 + threadIdx.x;   // grid exact: 6250*256
    const int node = gt >> 4;                          // 100000 nodes
    const int ch   = gt & 15;                          // 16B chunk within row
    const int end  = offsets[node];
    int i = end - counts[node];
    float acc[8];
    #pragma unroll
    for (int j = 0; j < 8; j++) acc[j] = 0.f;
    const uint4* __restrict__ h16 = (const uint4*)h;   // 16 chunks per row
    for (; i + 2 <= end; i += 2) {
        int2 p0 = pairs[i], p1 = pairs[i + 1];
        uint4 r0 = h16[(size_t)p0.x * 16 + ch];
        uint4 r1 = h16[(size_t)p1.x * 16 + ch];
        float w0 = __int_as_float(p0.y), w1 = __int_as_float(p1.y);
        const f16* e0 = (const f16*)&r0;
        const f16* e1 = (const f16*)&r1;
        #pragma unroll
        for (int j = 0; j < 8; j++) acc[j] = fmaf(w0, (float)e0[j], acc[j]);
        #pragma unroll
        for (int j = 0; j < 8; j++) acc[j] = fmaf(w1, (float)e1[j], acc[j]);
    }
    if (i < end) {
        int2 p0 = pairs[i];
        uint4 r0 = h16[(size_t)p0.x * 16 + ch];
        float w0 = __int_as_float(p0.y);
        const f16* e0 = (const f16*)&r0;
        #pragma unroll
        for (int j = 0; j < 8; j++) acc[j] = fmaf(w0, (float)e0[j], acc[j]);
    }
    union { f16 hh[8]; uint4 u; } cv;
    #pragma unroll
    for (int j = 0; j < 8; j++) cv.hh[j] = (f16)acc[j];
    ((uint4*)out)[(size_t)node * 16 + ch] = cv.u;
}

// ---------------------------------------------------------------------------
// Weight packing into MFMA fragment order (fp16).
// pack[(kk*CT+ct)*64 + lane][j] = W[kk*32 + (lane>>4)*8 + j][ct*16 + (lane&15)]
// ---------------------------------------------------------------------------
__global__ __launch_bounds__(256) void prep_pack(const float* __restrict__ W1,
                                                 const float* __restrict__ W2,
                                                 const float* __restrict__ Wrel1,
                                                 const float* __restrict__ Wroot1,
                                                 const float* __restrict__ Wrel2,
                                                 const float* __restrict__ Wroot2,
                                                 const float* __restrict__ Wd1,
                                                 const float* __restrict__ Wd2,
                                                 f16* __restrict__ pack)
{
    int t = blockIdx.x * 256 + threadIdx.x;   // grid exact: 151552/256 = 592
    float v;
    if (t < 32768) {                          // enc1: W1 [256,128], CT=8
        int l = t;
        int j = l & 7, lane = (l >> 3) & 63, ct = (l >> 9) & 7, kk = l >> 12;
        int k = kk * 32 + ((lane >> 4) << 3) + j, c = (ct << 4) + (lane & 15);
        v = W1[k * 128 + c];
    } else if (t < 49152) {                   // enc2: W2 [128,128], CT=8
        int l = t - 32768;
        int j = l & 7, lane = (l >> 3) & 63, ct = (l >> 9) & 7, kk = l >> 12;
        int k = kk * 32 + ((lane >> 4) << 3) + j, c = (ct << 4) + (lane & 15);
        v = W2[k * 128 + c];
    } else if (t < 81920) {                   // conv1: [Wrel1;Wroot1] K=256, CT=8
        int l = t - 49152;
        int j = l & 7, lane = (l >> 3) & 63, ct = (l >> 9) & 7, kk = l >> 12;
        int k = kk * 32 + ((lane >> 4) << 3) + j, c = (ct << 4) + (lane & 15);
        v = (k < 128) ? Wrel1[k * 128 + c] : Wroot1[(k - 128) * 128 + c];
    } else if (t < 114688) {                  // conv2
        int l = t - 81920;
        int j = l & 7, lane = (l >> 3) & 63, ct = (l >> 9) & 7, kk = l >> 12;
        int k = kk * 32 + ((lane >> 4) << 3) + j, c = (ct << 4) + (lane & 15);
        v = (k < 128) ? Wrel2[k * 128 + c] : Wroot2[(k - 128) * 128 + c];
    } else if (t < 118784) {                  // dec1: Wd1 [32,128], CT=8, kk=0
        int l = t - 114688;
        int j = l & 7, lane = (l >> 3) & 63, ct = (l >> 9) & 7;
        int k = ((lane >> 4) << 3) + j, c = (ct << 4) + (lane & 15);
        v = Wd1[k * 128 + c];
    } else {                                  // dec2: Wd2 [128,256], CT=16
        int l = t - 118784;
        int j = l & 7, lane = (l >> 3) & 63, ct = (l >> 9) & 15, kk = l >> 13;
        int k = kk * 32 + ((lane >> 4) << 3) + j, c = (ct << 4) + (lane & 15);
        v = Wd2[k * 256 + c];
    }
    pack[t] = (f16)v;
}

// ---------------------------------------------------------------------------
// MFMA GEMM building blocks. 64 nodes/block, 4 waves, wave = 16 nodes.
// ---------------------------------------------------------------------------
template<int C>
__device__ __forceinline__ void stage_tile(const float* __restrict__ src, int nbase,
                                           f16* lds, int ldr, int colofs)
{
    const int t = threadIdx.x;
    #pragma unroll
    for (int i = 0; i < (64 * C / 4) / 256; i++) {
        int elem = t + i * 256;
        int row = elem / (C / 4);
        int c4  = elem % (C / 4);
        int srow = nbase + row; if (srow >= NN) srow = NN - 1;
        float4 v = *(const float4*)(src + (size_t)srow * C + c4 * 4);
        union { f16 h[4]; uint2 u; } cv;
        cv.h[0] = (f16)v.x; cv.h[1] = (f16)v.y; cv.h[2] = (f16)v.z; cv.h[3] = (f16)v.w;
        *(uint2*)&lds[row * ldr + colofs + c4 * 4] = cv.u;
    }
}

template<int C>
__device__ __forceinline__ void stage_tile_f16(const f16* __restrict__ src, int nbase,
                                               f16* lds, int ldr, int colofs)
{
    const int t = threadIdx.x;
    #pragma unroll
    for (int i = 0; i < (64 * C / 4) / 256; i++) {
        int elem = t + i * 256;
        int row = elem / (C / 4);
        int c4  = elem % (C / 4);
        int srow = nbase + row; if (srow >= NN) srow = NN - 1;
        uint2 v = *(const uint2*)(src + (size_t)srow * C + c4 * 4);
        *(uint2*)&lds[row * ldr + colofs + c4 * 4] = v;
    }
}

template<int K, int CT>
__device__ __forceinline__ void wave_gemm(const f16* lds, int ldr,
                                          const f16x8* __restrict__ wp, f32x4 acc[CT])
{
    const int lane = threadIdx.x & 63;
    const int wrow = (threadIdx.x >> 6) * 16;
    const int arow = wrow + (lane & 15);
    const int kofs = (lane >> 4) << 3;
    #pragma unroll
    for (int kk = 0; kk < K / 32; kk++) {
        f16x8 a = *(const f16x8*)&lds[arow * ldr + kk * 32 + kofs];
        #pragma unroll
        for (int ct = 0; ct < CT; ct++) {
            f16x8 b = wp[(kk * CT + ct) * 64 + lane];
            acc[ct] = mfma16(a, b, acc[ct]);
        }
    }
}

template<int CT>
__device__ __forceinline__ void zacc(f32x4 acc[CT])
{
    #pragma unroll
    for (int ct = 0; ct < CT; ct++) acc[ct] = f32x4{0.f, 0.f, 0.f, 0.f};
}

// C/D layout (m89): col = lane&15, row = (lane>>4)*4 + reg
template<int CT, bool RELU>
__device__ __forceinline__ void store_f32(float* __restrict__ dst, int OUTC, int nbase,
                                          const float* __restrict__ bias, f32x4 acc[CT])
{
    const int lane = threadIdx.x & 63;
    const int wrow = (threadIdx.x >> 6) * 16;
    #pragma unroll
    for (int ct = 0; ct < CT; ct++) {
        int c = ct * 16 + (lane & 15);
        float bv = bias[c];
        #pragma unroll
        for (int r = 0; r < 4; r++) {
            int node = nbase + wrow + ((lane >> 4) << 2) + r;
            if (node < NN) {
                float v = acc[ct][r] + bv;
                if (RELU) v = frelu(v);
                dst[(size_t)node * OUTC + c] = v;
            }
        }
    }
}

template<int CT, bool RELU>
__device__ __forceinline__ void store_f16g(f16* __restrict__ dst, int OUTC, int nbase,
                                           const float* __restrict__ bias, f32x4 acc[CT])
{
    const int lane = threadIdx.x & 63;
    const int wrow = (threadIdx.x >> 6) * 16;
    #pragma unroll
    for (int ct = 0; ct < CT; ct++) {
        int c = ct * 16 + (lane & 15);
        float bv = bias[c];
        #pragma unroll
        for (int r = 0; r < 4; r++) {
            int node = nbase + wrow + ((lane >> 4) << 2) + r;
            if (node < NN) {
                float v = acc[ct][r] + bv;
                if (RELU) v = frelu(v);
                dst[(size_t)node * OUTC + c] = (f16)v;
            }
        }
    }
}

template<int CT>
__device__ __forceinline__ void store_lds_f16(f16* lds, int ldr,
                                              const float* __restrict__ bias, f32x4 acc[CT])
{
    const int lane = threadIdx.x & 63;
    const int wrow = (threadIdx.x >> 6) * 16;
    #pragma unroll
    for (int ct = 0; ct < CT; ct++) {
        int c = ct * 16 + (lane & 15);
        float bv = bias[c];
        #pragma unroll
        for (int r = 0; r < 4; r++) {
            int row = wrow + ((lane >> 4) << 2) + r;
            lds[row * ldr + c] = (f16)frelu(acc[ct][r] + bv);
        }
    }
}

// ---------------------------------------------------------------------------
// Encoder: h = relu(relu(x@W1+b1)@W2+b2) -> fp16 h.
// ---------------------------------------------------------------------------
__global__ __launch_bounds__(256) void enc_mfma(const float* __restrict__ x,
                                                const f16x8* __restrict__ wp1,
                                                const f16x8* __restrict__ wp2,
                                                const float* __restrict__ b1,
                                                const float* __restrict__ b2,
                                                f16* __restrict__ out)
{
    __shared__ __align__(16) f16 xs[64 * 264];
    __shared__ __align__(16) f16 h1[64 * 136];
    const int nbase = blockIdx.x * 64;
    stage_tile<256>(x, nbase, xs, 264, 0);
    __syncthreads();
    f32x4 acc[8];
    zacc<8>(acc);
    wave_gemm<256, 8>(xs, 264, wp1, acc);
    store_lds_f16<8>(h1, 136, b1, acc);
    __syncthreads();
    zacc<8>(acc);
    wave_gemm<128, 8>(h1, 136, wp2, acc);
    store_f16g<8, true>(out, 128, nbase, b2, acc);
}

// ---------------------------------------------------------------------------
// GraphConv combine: out = relu([agg|h] @ [Wrel;Wroot] + brel), fp16 in/out.
// ---------------------------------------------------------------------------
__global__ __launch_bounds__(256) void conv_mfma(const f16* __restrict__ agg,
                                                 const f16* __restrict__ h,
                                                 const f16x8* __restrict__ wp,
                                                 const float* __restrict__ brel,
                                                 f16* __restrict__ out)
{
    __shared__ __align__(16) f16 as_[64 * 264];
    const int nbase = blockIdx.x * 64;
    stage_tile_f16<128>(agg, nbase, as_, 264, 0);
    stage_tile_f16<128>(h,   nbase, as_, 264, 128);
    __syncthreads();
    f32x4 acc[8];
    zacc<8>(acc);
    wave_gemm<256, 8>(as_, 264, wp, acc);
    store_f16g<8, true>(out, 128, nbase, brel, acc);
}

// ---------------------------------------------------------------------------
// Heads (f32 math, f16 h input): mu/logvar. 32 nodes/block, 128 threads.
// ---------------------------------------------------------------------------
__global__ __launch_bounds__(128) void heads_kernel(const f16* __restrict__ h,
                                                    const float* __restrict__ Wmu, const float* __restrict__ bmu,
                                                    const float* __restrict__ Wlv, const float* __restrict__ blv,
                                                    float* __restrict__ out)
{
    __shared__ __align__(16) float hs[32 * 128];
    const int t = threadIdx.x;
    const int nbase = blockIdx.x * 32;
    #pragma unroll
    for (int i = 0; i < 8; i++) {
        int elem = t + i * 128;
        int row = elem >> 5;
        int c4  = elem & 31;
        union { f16 h[4]; uint2 u; } cv;
        cv.u = *(const uint2*)(h + (size_t)(nbase + row) * 128 + c4 * 4);
        float4 v = make_float4((float)cv.h[0], (float)cv.h[1], (float)cv.h[2], (float)cv.h[3]);
        *(float4*)&hs[row * 128 + c4 * 4] = v;
    }
    __syncthreads();
    const int c0 = (t & 15) * 4;
    const int n0 = (t >> 4) * 4;
    const bool is_mu = (c0 < 32);
    const float* W = is_mu ? Wmu : Wlv;
    const float* b = is_mu ? bmu : blv;
    const int cc = c0 & 31;
    float acc[4][4];
    #pragma unroll
    for (int n = 0; n < 4; n++)
        #pragma unroll
        for (int j = 0; j < 4; j++) acc[n][j] = 0.f;
    for (int k = 0; k < 128; k += 4) {
        float4 w0 = *(const float4*)(W + (size_t)(k + 0) * 32 + cc);
        float4 w1 = *(const float4*)(W + (size_t)(k + 1) * 32 + cc);
        float4 w2 = *(const float4*)(W + (size_t)(k + 2) * 32 + cc);
        float4 w3 = *(const float4*)(W + (size_t)(k + 3) * 32 + cc);
        #pragma unroll
        for (int n = 0; n < 4; n++) {
            float4 xv = *(const float4*)(&hs[(n0 + n) * 128 + k]);
            acc[n][0] += xv.x * w0.x + xv.y * w1.x + xv.z * w2.x + xv.w * w3.x;
            acc[n][1] += xv.x * w0.y + xv.y * w1.y + xv.z * w2.y + xv.w * w3.y;
            acc[n][2] += xv.x * w0.z + xv.y * w1.z + xv.z * w2.z + xv.w * w3.z;
            acc[n][3] += xv.x * w0.w + xv.y * w1.w + xv.z * w2.w + xv.w * w3.w;
        }
    }
    float4 bv = *(const float4*)(b + cc);
    float* base = out + (is_mu ? (size_t)25600000 : (size_t)28800000);
    #pragma unroll
    for (int n = 0; n < 4; n++) {
        float4 r;
        r.x = acc[n][0] + bv.x;
        r.y = acc[n][1] + bv.y;
        r.z = acc[n][2] + bv.z;
        r.w = acc[n][3] + bv.w;
        *(float4*)(base + (size_t)(nbase + n0 + n) * 32 + cc) = r;
    }
}

// z = mu + eps * exp(0.5*logvar)
__global__ __launch_bounds__(256) void reparam_kernel(const float* __restrict__ eps,
                                                      float* __restrict__ out)
{
    int i = blockIdx.x * 256 + threadIdx.x;
    float mu = out[25600000 + i];
    float lv = out[28800000 + i];
    out[32000000 + i] = fmaf(eps[i], expf(0.5f * lv), mu);
}

// ---------------------------------------------------------------------------
// Decoder: x_recon = relu(z@Wd1+bd1)@Wd2 + bd2, two fused MFMA layers, f32 out.
// ---------------------------------------------------------------------------
__global__ __launch_bounds__(256) void dec_mfma(const float* __restrict__ z,
                                                const f16x8* __restrict__ wp1,
                                                const float* __restrict__ bd1,
                                                const f16x8* __restrict__ wp2,
                                                const float* __restrict__ bd2,
                                                float* __restrict__ out)
{
    __shared__ __align__(16) f16 zs[64 * 40];
    __shared__ __align__(16) f16 hd[64 * 136];
    const int nbase = blockIdx.x * 64;
    stage_tile<32>(z, nbase, zs, 40, 0);
    __syncthreads();
    f32x4 acc[8];
    zacc<8>(acc);
    wave_gemm<32, 8>(zs, 40, wp1, acc);
    store_lds_f16<8>(hd, 136, bd1, acc);
    __syncthreads();
    f32x4 acc2[16];
    zacc<16>(acc2);
    wave_gemm<128, 16>(hd, 136, wp2, acc2);
    store_f32<16, false>(out, 256, nbase, bd2, acc2);
}

// ---------------------------------------------------------------------------
extern "C" void kernel_launch(void* const* d_in, const int* in_sizes, int n_in,
                              void* d_out, int out_size, void* d_ws, size_t ws_size,
                              hipStream_t stream)
{
    const float* x     = (const float*)d_in[0];
    const int*   ei    = (const int*)d_in[1];
    const float* ea    = (const float*)d_in[2];
    const float* W1    = (const float*)d_in[3];
    const float* b1    = (const float*)d_in[4];
    const float* W2    = (const float*)d_in[5];
    const float* b2    = (const float*)d_in[6];
    const float* Wrel1 = (const float*)d_in[7];
    const float* brel1 = (const float*)d_in[8];
    const float* Wroot1= (const float*)d_in[9];
    const float* Wrel2 = (const float*)d_in[10];
    const float* brel2 = (const float*)d_in[11];
    const float* Wroot2= (const float*)d_in[12];
    const float* Wmu   = (const float*)d_in[13];
    const float* bmu   = (const float*)d_in[14];
    const float* Wlv   = (const float*)d_in[15];
    const float* blv   = (const float*)d_in[16];
    const float* Wd1   = (const float*)d_in[17];
    const float* bd1   = (const float*)d_in[18];
    const float* Wd2   = (const float*)d_in[19];
    const float* bd2   = (const float*)d_in[20];
    const float* eps   = (const float*)d_in[21];
    float* out = (float*)d_out;

    // fp16 h ping-pong buffers live in d_out's x_recon region (dead until dec).
    f16* B0 = (f16*)out;                // [N,128] f16 = 25.6 MB
    f16* B1 = B0 + 12800000;            // [N,128] f16

    char* ws = (char*)d_ws;
    int*   counts  = (int*)  (ws);                 // [N]      400 KB
    int*   offsets = (int*)  (ws + 400000);        // [N]      400 KB
    int*   bsums   = (int*)  (ws + 800000);        // [98]
    int2*  pairs   = (int2*) (ws + 801024);        // [E]      12.8 MB
    f16*   pack    = (f16*)  (ws + 13601024);      // 151552 halves

    const f16x8* wp_enc1  = (const f16x8*)(pack);
    const f16x8* wp_enc2  = (const f16x8*)(pack + 32768);
    const f16x8* wp_conv1 = (const f16x8*)(pack + 49152);
    const f16x8* wp_conv2 = (const f16x8*)(pack + 81920);
    const f16x8* wp_dec1  = (const f16x8*)(pack + 114688);
    const f16x8* wp_dec2  = (const f16x8*)(pack + 118784);

    const int* src = ei;          // edge_index row 0
    const int* dst = ei + EE;     // edge_index row 1

    // --- weight packing + CSR build ---
    prep_pack<<<592, 256, 0, stream>>>(W1, W2, Wrel1, Wroot1, Wrel2, Wroot2, Wd1, Wd2, pack);
    hipMemsetAsync(counts, 0, NN * sizeof(int), stream);
    count_deg<<<EE / 256, 256, 0, stream>>>(dst, counts);
    scan_blocks<<<98, 256, 0, stream>>>(counts, offsets, bsums);
    scan_sums<<<1, 128, 0, stream>>>(bsums);
    scan_add<<<98, 256, 0, stream>>>(offsets, bsums);
    fill_csr<<<EE / 256, 256, 0, stream>>>(src, dst, ea, offsets, pairs);

    // --- forward pass ---
    enc_mfma<<<1563, 256, 0, stream>>>(x, wp_enc1, wp_enc2, b1, b2, B0);
    agg_q<<<6250, 256, 0, stream>>>(B0, pairs, offsets, counts, B1);
    conv_mfma<<<1563, 256, 0, stream>>>(B1, B0, wp_conv1, brel1, B1);
    agg_q<<<6250, 256, 0, stream>>>(B1, pairs, offsets, counts, B0);
    conv_mfma<<<1563, 256, 0, stream>>>(B0, B1, wp_conv2, brel2, B0);
    heads_kernel<<<3125, 128, 0, stream>>>(B0, Wmu, bmu, Wlv, blv, out);
    reparam_kernel<<<12500, 256, 0, stream>>>(eps, out);
    dec_mfma<<<1563, 256, 0, stream>>>(out + 32000000, wp_dec1, bd1, wp_dec2, bd2, out);
}

// Round 6
// 493.865 us; speedup vs baseline: 2.2424x; 1.0676x over previous
//
#include <hip/hip_runtime.h>
#include <math.h>

#define NN 100000
#define EE 1600000

typedef _Float16 f16;
typedef __attribute__((ext_vector_type(2))) _Float16 f16x2;
typedef __attribute__((ext_vector_type(8))) _Float16 f16x8;
typedef __attribute__((ext_vector_type(4))) float f32x4;
typedef unsigned int u32;

__device__ __forceinline__ float frelu(float v){ return v > 0.f ? v : 0.f; }

__device__ __forceinline__ f32x4 mfma16(f16x8 a, f16x8 b, f32x4 c){
    return __builtin_amdgcn_mfma_f32_16x16x32_f16(a, b, c, 0, 0, 0);
}

// ---------------------------------------------------------------------------
// CSR build: degree histogram -> exclusive scan -> bucket fill
// ---------------------------------------------------------------------------
__global__ __launch_bounds__(256) void count_deg(const int* __restrict__ dst,
                                                 int* __restrict__ counts)
{
    int e = blockIdx.x * 256 + threadIdx.x;
    atomicAdd(&counts[dst[e]], 1);
}

__global__ __launch_bounds__(256) void scan_blocks(const int* __restrict__ counts,
                                                   int* __restrict__ offsets,
                                                   int* __restrict__ bsums)
{
    __shared__ int lds[256];
    const int t = threadIdx.x, b = blockIdx.x;
    const int base = b * 1024 + t * 4;
    int v[4];
    #pragma unroll
    for (int i = 0; i < 4; i++) { int idx = base + i; v[i] = (idx < NN) ? counts[idx] : 0; }
    int s = v[0] + v[1] + v[2] + v[3];
    lds[t] = s;
    __syncthreads();
    for (int off = 1; off < 256; off <<= 1) {
        int y = (t >= off) ? lds[t - off] : 0;
        __syncthreads();
        lds[t] += y;
        __syncthreads();
    }
    int run = (t > 0) ? lds[t - 1] : 0;
    if (t == 255) bsums[b] = lds[255];
    #pragma unroll
    for (int i = 0; i < 4; i++) { int idx = base + i; if (idx < NN) offsets[idx] = run; run += v[i]; }
}

__global__ __launch_bounds__(128) void scan_sums(int* __restrict__ bsums)
{
    __shared__ int lds[128];
    const int t = threadIdx.x;
    lds[t] = (t < 98) ? bsums[t] : 0;
    __syncthreads();
    for (int off = 1; off < 128; off <<= 1) {
        int y = (t >= off) ? lds[t - off] : 0;
        __syncthreads();
        lds[t] += y;
        __syncthreads();
    }
    if (t < 98) bsums[t] = (t > 0) ? lds[t - 1] : 0;
}

__global__ __launch_bounds__(256) void scan_add(int* __restrict__ offsets,
                                                const int* __restrict__ bsums)
{
    const int b = blockIdx.x;
    const int add = bsums[b];
    const int base = b * 1024 + threadIdx.x * 4;
    #pragma unroll
    for (int i = 0; i < 4; i++) { int idx = base + i; if (idx < NN) offsets[idx] += add; }
}

// ---------------------------------------------------------------------------
// Bucket fill, dst-range partitioned with XCD affinity.
// part = blockIdx.x & 7 == XCD id (round-robin dispatch, m09): each XCD's
// scattered writes land in a 1.6 MB window of pairs -> L2-resident lines
// accumulate all 8B stores before write-back (kills the 8x write-amp).
// dst/src/ea re-reads (8x logical) are L3-served after first touch.
// ---------------------------------------------------------------------------
__global__ __launch_bounds__(256) void fill_csr_part(const int* __restrict__ src,
                                                     const int* __restrict__ dst,
                                                     const float* __restrict__ ea,
                                                     int* __restrict__ offsets,
                                                     int2* __restrict__ pairs)
{
    const int part = blockIdx.x & 7;           // XCD-affine dst range
    const int cb   = blockIdx.x >> 3;          // 0..511 edge chunk
    const int lo   = part * 12500, hi = lo + 12500;
    const int ebase = cb * 3125;               // 1600000/512 = 3125 exact
    for (int e = ebase + threadIdx.x; e < ebase + 3125; e += 256) {
        int d = dst[e];
        if (d >= lo && d < hi) {
            int p = atomicAdd(&offsets[d], 1);
            pairs[p] = make_int2(src[e], __float_as_int(ea[e]));
        }
    }
}

// ---------------------------------------------------------------------------
// Aggregation: quarter-wave (16 lanes x 16B) per node. 4 nodes per wave,
// 1KB of gather data in flight per wave-instruction, v_fma_mix accumulate.
// ---------------------------------------------------------------------------
__global__ __launch_bounds__(256) void agg_q(const f16* __restrict__ h,
                                             const int2* __restrict__ pairs,
                                             const int* __restrict__ offsets,
                                             const int* __restrict__ counts,
                                             f16* __restrict__ out)
{
    const int gt   = blockIdx.x * 256 + threadIdx.x;   // grid exact: 6250*256
    const int node = gt >> 4;                          // 100000 nodes
    const int ch   = gt & 15;                          // 16B chunk within row
    const int end  = offsets[node];
    int i = end - counts[node];
    float acc[8];
    #pragma unroll
    for (int j = 0; j < 8; j++) acc[j] = 0.f;
    const uint4* __restrict__ h16 = (const uint4*)h;   // 16 chunks per row
    for (; i + 2 <= end; i += 2) {
        int2 p0 = pairs[i], p1 = pairs[i + 1];
        uint4 r0 = h16[(size_t)p0.x * 16 + ch];
        uint4 r1 = h16[(size_t)p1.x * 16 + ch];
        float w0 = __int_as_float(p0.y), w1 = __int_as_float(p1.y);
        const f16* e0 = (const f16*)&r0;
        const f16* e1 = (const f16*)&r1;
        #pragma unroll
        for (int j = 0; j < 8; j++) acc[j] = fmaf(w0, (float)e0[j], acc[j]);
        #pragma unroll
        for (int j = 0; j < 8; j++) acc[j] = fmaf(w1, (float)e1[j], acc[j]);
    }
    if (i < end) {
        int2 p0 = pairs[i];
        uint4 r0 = h16[(size_t)p0.x * 16 + ch];
        float w0 = __int_as_float(p0.y);
        const f16* e0 = (const f16*)&r0;
        #pragma unroll
        for (int j = 0; j < 8; j++) acc[j] = fmaf(w0, (float)e0[j], acc[j]);
    }
    union { f16 hh[8]; uint4 u; } cv;
    #pragma unroll
    for (int j = 0; j < 8; j++) cv.hh[j] = (f16)acc[j];
    ((uint4*)out)[(size_t)node * 16 + ch] = cv.u;
}

// ---------------------------------------------------------------------------
// Weight packing into MFMA fragment order (fp16).
// pack[(kk*CT+ct)*64 + lane][j] = W[kk*32 + (lane>>4)*8 + j][ct*16 + (lane&15)]
// ---------------------------------------------------------------------------
__global__ __launch_bounds__(256) void prep_pack(const float* __restrict__ W1,
                                                 const float* __restrict__ W2,
                                                 const float* __restrict__ Wrel1,
                                                 const float* __restrict__ Wroot1,
                                                 const float* __restrict__ Wrel2,
                                                 const float* __restrict__ Wroot2,
                                                 const float* __restrict__ Wd1,
                                                 const float* __restrict__ Wd2,
                                                 f16* __restrict__ pack)
{
    int t = blockIdx.x * 256 + threadIdx.x;   // grid exact: 151552/256 = 592
    float v;
    if (t < 32768) {                          // enc1: W1 [256,128], CT=8
        int l = t;
        int j = l & 7, lane = (l >> 3) & 63, ct = (l >> 9) & 7, kk = l >> 12;
        int k = kk * 32 + ((lane >> 4) << 3) + j, c = (ct << 4) + (lane & 15);
        v = W1[k * 128 + c];
    } else if (t < 49152) {                   // enc2: W2 [128,128], CT=8
        int l = t - 32768;
        int j = l & 7, lane = (l >> 3) & 63, ct = (l >> 9) & 7, kk = l >> 12;
        int k = kk * 32 + ((lane >> 4) << 3) + j, c = (ct << 4) + (lane & 15);
        v = W2[k * 128 + c];
    } else if (t < 81920) {                   // conv1: [Wrel1;Wroot1] K=256, CT=8
        int l = t - 49152;
        int j = l & 7, lane = (l >> 3) & 63, ct = (l >> 9) & 7, kk = l >> 12;
        int k = kk * 32 + ((lane >> 4) << 3) + j, c = (ct << 4) + (lane & 15);
        v = (k < 128) ? Wrel1[k * 128 + c] : Wroot1[(k - 128) * 128 + c];
    } else if (t < 114688) {                  // conv2
        int l = t - 81920;
        int j = l & 7, lane = (l >> 3) & 63, ct = (l >> 9) & 7, kk = l >> 12;
        int k = kk * 32 + ((lane >> 4) << 3) + j, c = (ct << 4) + (lane & 15);
        v = (k < 128) ? Wrel2[k * 128 + c] : Wroot2[(k - 128) * 128 + c];
    } else if (t < 118784) {                  // dec1: Wd1 [32,128], CT=8, kk=0
        int l = t - 114688;
        int j = l & 7, lane = (l >> 3) & 63, ct = (l >> 9) & 7;
        int k = ((lane >> 4) << 3) + j, c = (ct << 4) + (lane & 15);
        v = Wd1[k * 128 + c];
    } else {                                  // dec2: Wd2 [128,256], CT=16
        int l = t - 118784;
        int j = l & 7, lane = (l >> 3) & 63, ct = (l >> 9) & 15, kk = l >> 13;
        int k = kk * 32 + ((lane >> 4) << 3) + j, c = (ct << 4) + (lane & 15);
        v = Wd2[k * 256 + c];
    }
    pack[t] = (f16)v;
}

// ---------------------------------------------------------------------------
// MFMA GEMM building blocks. 64 nodes/block, 4 waves, wave = 16 nodes.
// ---------------------------------------------------------------------------
template<int C>
__device__ __forceinline__ void stage_tile(const float* __restrict__ src, int nbase,
                                           f16* lds, int ldr, int colofs)
{
    const int t = threadIdx.x;
    #pragma unroll
    for (int i = 0; i < (64 * C / 4) / 256; i++) {
        int elem = t + i * 256;
        int row = elem / (C / 4);
        int c4  = elem % (C / 4);
        int srow = nbase + row; if (srow >= NN) srow = NN - 1;
        float4 v = *(const float4*)(src + (size_t)srow * C + c4 * 4);
        union { f16 h[4]; uint2 u; } cv;
        cv.h[0] = (f16)v.x; cv.h[1] = (f16)v.y; cv.h[2] = (f16)v.z; cv.h[3] = (f16)v.w;
        *(uint2*)&lds[row * ldr + colofs + c4 * 4] = cv.u;
    }
}

template<int C>
__device__ __forceinline__ void stage_tile_f16(const f16* __restrict__ src, int nbase,
                                               f16* lds, int ldr, int colofs)
{
    const int t = threadIdx.x;
    #pragma unroll
    for (int i = 0; i < (64 * C / 4) / 256; i++) {
        int elem = t + i * 256;
        int row = elem / (C / 4);
        int c4  = elem % (C / 4);
        int srow = nbase + row; if (srow >= NN) srow = NN - 1;
        uint2 v = *(const uint2*)(src + (size_t)srow * C + c4 * 4);
        *(uint2*)&lds[row * ldr + colofs + c4 * 4] = v;
    }
}

template<int K, int CT>
__device__ __forceinline__ void wave_gemm(const f16* lds, int ldr,
                                          const f16x8* __restrict__ wp, f32x4 acc[CT])
{
    const int lane = threadIdx.x & 63;
    const int wrow = (threadIdx.x >> 6) * 16;
    const int arow = wrow + (lane & 15);
    const int kofs = (lane >> 4) << 3;
    #pragma unroll
    for (int kk = 0; kk < K / 32; kk++) {
        f16x8 a = *(const f16x8*)&lds[arow * ldr + kk * 32 + kofs];
        #pragma unroll
        for (int ct = 0; ct < CT; ct++) {
            f16x8 b = wp[(kk * CT + ct) * 64 + lane];
            acc[ct] = mfma16(a, b, acc[ct]);
        }
    }
}

template<int CT>
__device__ __forceinline__ void zacc(f32x4 acc[CT])
{
    #pragma unroll
    for (int ct = 0; ct < CT; ct++) acc[ct] = f32x4{0.f, 0.f, 0.f, 0.f};
}

// C/D layout (m89): col = lane&15, row = (lane>>4)*4 + reg
template<int CT, bool RELU>
__device__ __forceinline__ void store_f32(float* __restrict__ dst, int OUTC, int nbase,
                                          const float* __restrict__ bias, f32x4 acc[CT])
{
    const int lane = threadIdx.x & 63;
    const int wrow = (threadIdx.x >> 6) * 16;
    #pragma unroll
    for (int ct = 0; ct < CT; ct++) {
        int c = ct * 16 + (lane & 15);
        float bv = bias[c];
        #pragma unroll
        for (int r = 0; r < 4; r++) {
            int node = nbase + wrow + ((lane >> 4) << 2) + r;
            if (node < NN) {
                float v = acc[ct][r] + bv;
                if (RELU) v = frelu(v);
                dst[(size_t)node * OUTC + c] = v;
            }
        }
    }
}

template<int CT, bool RELU>
__device__ __forceinline__ void store_f16g(f16* __restrict__ dst, int OUTC, int nbase,
                                           const float* __restrict__ bias, f32x4 acc[CT])
{
    const int lane = threadIdx.x & 63;
    const int wrow = (threadIdx.x >> 6) * 16;
    #pragma unroll
    for (int ct = 0; ct < CT; ct++) {
        int c = ct * 16 + (lane & 15);
        float bv = bias[c];
        #pragma unroll
        for (int r = 0; r < 4; r++) {
            int node = nbase + wrow + ((lane >> 4) << 2) + r;
            if (node < NN) {
                float v = acc[ct][r] + bv;
                if (RELU) v = frelu(v);
                dst[(size_t)node * OUTC + c] = (f16)v;
            }
        }
    }
}

template<int CT>
__device__ __forceinline__ void store_lds_f16(f16* lds, int ldr,
                                              const float* __restrict__ bias, f32x4 acc[CT])
{
    const int lane = threadIdx.x & 63;
    const int wrow = (threadIdx.x >> 6) * 16;
    #pragma unroll
    for (int ct = 0; ct < CT; ct++) {
        int c = ct * 16 + (lane & 15);
        float bv = bias[c];
        #pragma unroll
        for (int r = 0; r < 4; r++) {
            int row = wrow + ((lane >> 4) << 2) + r;
            lds[row * ldr + c] = (f16)frelu(acc[ct][r] + bv);
        }
    }
}

// ---------------------------------------------------------------------------
// Encoder: h = relu(relu(x@W1+b1)@W2+b2) -> fp16 h.
// ---------------------------------------------------------------------------
__global__ __launch_bounds__(256) void enc_mfma(const float* __restrict__ x,
                                                const f16x8* __restrict__ wp1,
                                                const f16x8* __restrict__ wp2,
                                                const float* __restrict__ b1,
                                                const float* __restrict__ b2,
                                                f16* __restrict__ out)
{
    __shared__ __align__(16) f16 xs[64 * 264];
    __shared__ __align__(16) f16 h1[64 * 136];
    const int nbase = blockIdx.x * 64;
    stage_tile<256>(x, nbase, xs, 264, 0);
    __syncthreads();
    f32x4 acc[8];
    zacc<8>(acc);
    wave_gemm<256, 8>(xs, 264, wp1, acc);
    store_lds_f16<8>(h1, 136, b1, acc);
    __syncthreads();
    zacc<8>(acc);
    wave_gemm<128, 8>(h1, 136, wp2, acc);
    store_f16g<8, true>(out, 128, nbase, b2, acc);
}

// ---------------------------------------------------------------------------
// GraphConv combine: out = relu([agg|h] @ [Wrel;Wroot] + brel), fp16 in/out.
// ---------------------------------------------------------------------------
__global__ __launch_bounds__(256) void conv_mfma(const f16* __restrict__ agg,
                                                 const f16* __restrict__ h,
                                                 const f16x8* __restrict__ wp,
                                                 const float* __restrict__ brel,
                                                 f16* __restrict__ out)
{
    __shared__ __align__(16) f16 as_[64 * 264];
    const int nbase = blockIdx.x * 64;
    stage_tile_f16<128>(agg, nbase, as_, 264, 0);
    stage_tile_f16<128>(h,   nbase, as_, 264, 128);
    __syncthreads();
    f32x4 acc[8];
    zacc<8>(acc);
    wave_gemm<256, 8>(as_, 264, wp, acc);
    store_f16g<8, true>(out, 128, nbase, brel, acc);
}

// ---------------------------------------------------------------------------
// Heads (f32 math, f16 h input): mu/logvar. 32 nodes/block, 128 threads.
// ---------------------------------------------------------------------------
__global__ __launch_bounds__(128) void heads_kernel(const f16* __restrict__ h,
                                                    const float* __restrict__ Wmu, const float* __restrict__ bmu,
                                                    const float* __restrict__ Wlv, const float* __restrict__ blv,
                                                    float* __restrict__ out)
{
    __shared__ __align__(16) float hs[32 * 128];
    const int t = threadIdx.x;
    const int nbase = blockIdx.x * 32;
    #pragma unroll
    for (int i = 0; i < 8; i++) {
        int elem = t + i * 128;
        int row = elem >> 5;
        int c4  = elem & 31;
        union { f16 h[4]; uint2 u; } cv;
        cv.u = *(const uint2*)(h + (size_t)(nbase + row) * 128 + c4 * 4);
        float4 v = make_float4((float)cv.h[0], (float)cv.h[1], (float)cv.h[2], (float)cv.h[3]);
        *(float4*)&hs[row * 128 + c4 * 4] = v;
    }
    __syncthreads();
    const int c0 = (t & 15) * 4;
    const int n0 = (t >> 4) * 4;
    const bool is_mu = (c0 < 32);
    const float* W = is_mu ? Wmu : Wlv;
    const float* b = is_mu ? bmu : blv;
    const int cc = c0 & 31;
    float acc[4][4];
    #pragma unroll
    for (int n = 0; n < 4; n++)
        #pragma unroll
        for (int j = 0; j < 4; j++) acc[n][j] = 0.f;
    for (int k = 0; k < 128; k += 4) {
        float4 w0 = *(const float4*)(W + (size_t)(k + 0) * 32 + cc);
        float4 w1 = *(const float4*)(W + (size_t)(k + 1) * 32 + cc);
        float4 w2 = *(const float4*)(W + (size_t)(k + 2) * 32 + cc);
        float4 w3 = *(const float4*)(W + (size_t)(k + 3) * 32 + cc);
        #pragma unroll
        for (int n = 0; n < 4; n++) {
            float4 xv = *(const float4*)(&hs[(n0 + n) * 128 + k]);
            acc[n][0] += xv.x * w0.x + xv.y * w1.x + xv.z * w2.x + xv.w * w3.x;
            acc[n][1] += xv.x * w0.y + xv.y * w1.y + xv.z * w2.y + xv.w * w3.y;
            acc[n][2] += xv.x * w0.z + xv.y * w1.z + xv.z * w2.z + xv.w * w3.z;
            acc[n][3] += xv.x * w0.w + xv.y * w1.w + xv.z * w2.w + xv.w * w3.w;
        }
    }
    float4 bv = *(const float4*)(b + cc);
    float* base = out + (is_mu ? (size_t)25600000 : (size_t)28800000);
    #pragma unroll
    for (int n = 0; n < 4; n++) {
        float4 r;
        r.x = acc[n][0] + bv.x;
        r.y = acc[n][1] + bv.y;
        r.z = acc[n][2] + bv.z;
        r.w = acc[n][3] + bv.w;
        *(float4*)(base + (size_t)(nbase + n0 + n) * 32 + cc) = r;
    }
}

// z = mu + eps * exp(0.5*logvar)
__global__ __launch_bounds__(256) void reparam_kernel(const float* __restrict__ eps,
                                                      float* __restrict__ out)
{
    int i = blockIdx.x * 256 + threadIdx.x;
    float mu = out[25600000 + i];
    float lv = out[28800000 + i];
    out[32000000 + i] = fmaf(eps[i], expf(0.5f * lv), mu);
}

// ---------------------------------------------------------------------------
// Decoder: x_recon = relu(z@Wd1+bd1)@Wd2 + bd2, two fused MFMA layers, f32 out.
// ---------------------------------------------------------------------------
__global__ __launch_bounds__(256) void dec_mfma(const float* __restrict__ z,
                                                const f16x8* __restrict__ wp1,
                                                const float* __restrict__ bd1,
                                                const f16x8* __restrict__ wp2,
                                                const float* __restrict__ bd2,
                                                float* __restrict__ out)
{
    __shared__ __align__(16) f16 zs[64 * 40];
    __shared__ __align__(16) f16 hd[64 * 136];
    const int nbase = blockIdx.x * 64;
    stage_tile<32>(z, nbase, zs, 40, 0);
    __syncthreads();
    f32x4 acc[8];
    zacc<8>(acc);
    wave_gemm<32, 8>(zs, 40, wp1, acc);
    store_lds_f16<8>(hd, 136, bd1, acc);
    __syncthreads();
    f32x4 acc2[16];
    zacc<16>(acc2);
    wave_gemm<128, 16>(hd, 136, wp2, acc2);
    store_f32<16, false>(out, 256, nbase, bd2, acc2);
}

// ---------------------------------------------------------------------------
extern "C" void kernel_launch(void* const* d_in, const int* in_sizes, int n_in,
                              void* d_out, int out_size, void* d_ws, size_t ws_size,
                              hipStream_t stream)
{
    const float* x     = (const float*)d_in[0];
    const int*   ei    = (const int*)d_in[1];
    const float* ea    = (const float*)d_in[2];
    const float* W1    = (const float*)d_in[3];
    const float* b1    = (const float*)d_in[4];
    const float* W2    = (const float*)d_in[5];
    const float* b2    = (const float*)d_in[6];
    const float* Wrel1 = (const float*)d_in[7];
    const float* brel1 = (const float*)d_in[8];
    const float* Wroot1= (const float*)d_in[9];
    const float* Wrel2 = (const float*)d_in[10];
    const float* brel2 = (const float*)d_in[11];
    const float* Wroot2= (const float*)d_in[12];
    const float* Wmu   = (const float*)d_in[13];
    const float* bmu   = (const float*)d_in[14];
    const float* Wlv   = (const float*)d_in[15];
    const float* blv   = (const float*)d_in[16];
    const float* Wd1   = (const float*)d_in[17];
    const float* bd1   = (const float*)d_in[18];
    const float* Wd2   = (const float*)d_in[19];
    const float* bd2   = (const float*)d_in[20];
    const float* eps   = (const float*)d_in[21];
    float* out = (float*)d_out;

    // fp16 h ping-pong buffers live in d_out's x_recon region (dead until dec).
    f16* B0 = (f16*)out;                // [N,128] f16 = 25.6 MB
    f16* B1 = B0 + 12800000;            // [N,128] f16

    char* ws = (char*)d_ws;
    int*   counts  = (int*)  (ws);                 // [N]      400 KB
    int*   offsets = (int*)  (ws + 400000);        // [N]      400 KB
    int*   bsums   = (int*)  (ws + 800000);        // [98]
    int2*  pairs   = (int2*) (ws + 801024);        // [E]      12.8 MB
    f16*   pack    = (f16*)  (ws + 13601024);      // 151552 halves

    const f16x8* wp_enc1  = (const f16x8*)(pack);
    const f16x8* wp_enc2  = (const f16x8*)(pack + 32768);
    const f16x8* wp_conv1 = (const f16x8*)(pack + 49152);
    const f16x8* wp_conv2 = (const f16x8*)(pack + 81920);
    const f16x8* wp_dec1  = (const f16x8*)(pack + 114688);
    const f16x8* wp_dec2  = (const f16x8*)(pack + 118784);

    const int* src = ei;          // edge_index row 0
    const int* dst = ei + EE;     // edge_index row 1

    // --- weight packing + CSR build ---
    prep_pack<<<592, 256, 0, stream>>>(W1, W2, Wrel1, Wroot1, Wrel2, Wroot2, Wd1, Wd2, pack);
    hipMemsetAsync(counts, 0, NN * sizeof(int), stream);
    count_deg<<<EE / 256, 256, 0, stream>>>(dst, counts);
    scan_blocks<<<98, 256, 0, stream>>>(counts, offsets, bsums);
    scan_sums<<<1, 128, 0, stream>>>(bsums);
    scan_add<<<98, 256, 0, stream>>>(offsets, bsums);
    fill_csr_part<<<4096, 256, 0, stream>>>(src, dst, ea, offsets, pairs);

    // --- forward pass ---
    enc_mfma<<<1563, 256, 0, stream>>>(x, wp_enc1, wp_enc2, b1, b2, B0);
    agg_q<<<6250, 256, 0, stream>>>(B0, pairs, offsets, counts, B1);
    conv_mfma<<<1563, 256, 0, stream>>>(B1, B0, wp_conv1, brel1, B1);
    agg_q<<<6250, 256, 0, stream>>>(B1, pairs, offsets, counts, B0);
    conv_mfma<<<1563, 256, 0, stream>>>(B0, B1, wp_conv2, brel2, B0);
    heads_kernel<<<3125, 128, 0, stream>>>(B0, Wmu, bmu, Wlv, blv, out);
    reparam_kernel<<<12500, 256, 0, stream>>>(eps, out);
    dec_mfma<<<1563, 256, 0, stream>>>(out + 32000000, wp_dec1, bd1, wp_dec2, bd2, out);
}